// Round 6
// baseline (464.666 us; speedup 1.0000x reference)
//
#include <hip/hip_runtime.h>
#include <math.h>

#define NB 8
#define CDIM 256
#define HWD 1024
#define NH 8
#define HD 32
#define NN 102
#define GD 64

typedef __attribute__((ext_vector_type(8))) short bf16x8;
typedef __attribute__((ext_vector_type(4))) float f32x4;

__device__ inline short f2bf(float f) {
  union { float f; unsigned u; } v; v.f = f;
  unsigned r = v.u + 0x7fffu + ((v.u >> 16) & 1u);
  return (short)(r >> 16);
}
__device__ inline float bf2f(short s) {
  union { unsigned u; float f; } v;
  v.u = ((unsigned)(unsigned short)s) << 16;
  return v.f;
}

// ---------------- split weights into hi/lo bf16 ([n][k] layout kept) ----------------
__global__ __launch_bounds__(256) void wsplit_k(const float* __restrict__ w_qkv,
                                                const float* __restrict__ w_proj,
                                                short* __restrict__ wqh, short* __restrict__ wql,
                                                short* __restrict__ wph, short* __restrict__ wpl) {
  int t = blockIdx.x * 256 + threadIdx.x;
  if (t < 196608) {
    float v = w_qkv[t];
    short hi = f2bf(v);
    wqh[t] = hi; wql[t] = f2bf(v - bf2f(hi));
  } else {
    int u = t - 196608;
    float v = w_proj[u];
    short hi = f2bf(v);
    wph[u] = hi; wpl[u] = f2bf(v - bf2f(hi));
  }
}

// ---------------- x [b][c][p] -> xt hi/lo bf16 [b][p][c] ----------------
__global__ __launch_bounds__(256) void xsplit_k(const float* __restrict__ x,
                                                short* __restrict__ xth,
                                                short* __restrict__ xtl) {
  __shared__ float tile[64][65];
  int p0 = blockIdx.x * 64, c0 = blockIdx.y * 64, b = blockIdx.z;
  int t = threadIdx.x;
  {
    int g = t >> 6, p = t & 63;
#pragma unroll
    for (int i = 0; i < 16; ++i) {
      int cc = g * 16 + i;
      tile[cc][p] = x[((size_t)(b * 256 + c0 + cc)) * 1024 + p0 + p];
    }
  }
  __syncthreads();
  {
    int p = t >> 2, cs = (t & 3) * 16;
    size_t rb = ((size_t)(b * 1024 + p0 + p)) * 256 + c0 + cs;
#pragma unroll
    for (int g = 0; g < 4; ++g) {
      short4 hv, lv;
      float f0 = tile[cs + g * 4 + 0][p];
      float f1 = tile[cs + g * 4 + 1][p];
      float f2 = tile[cs + g * 4 + 2][p];
      float f3 = tile[cs + g * 4 + 3][p];
      hv.x = f2bf(f0); lv.x = f2bf(f0 - bf2f(hv.x));
      hv.y = f2bf(f1); lv.y = f2bf(f1 - bf2f(hv.y));
      hv.z = f2bf(f2); lv.z = f2bf(f2 - bf2f(hv.z));
      hv.w = f2bf(f3); lv.w = f2bf(f3 - bf2f(hv.w));
      *(short4*)(xth + rb + g * 4) = hv;
      *(short4*)(xtl + rb + g * 4) = lv;
    }
  }
}

// ---------------- prep: bf16-transposed GAT weights ----------------
__global__ __launch_bounds__(256) void prep_k(const float* __restrict__ g0W,
                                              const float* __restrict__ g1W,
                                              short* __restrict__ w0bT,
                                              short* __restrict__ w1bT) {
  int t = blockIdx.x * 256 + threadIdx.x;
  if (t < 16384) {
    int c = t >> 6, f = t & 63;
    w0bT[f * 256 + c] = f2bf(g0W[t]);
  } else if (t < 20480) {
    int u2 = t - 16384;
    int c = u2 >> 6, f = u2 & 63;
    w1bT[f * 64 + c] = f2bf(g1W[u2]);
  }
}

// ---------------- importance = unbiased variance over channels ----------------
__global__ __launch_bounds__(256) void importance_k(const float* __restrict__ x,
                                                    float* __restrict__ imp) {
  __shared__ float red[8][33];
  int bp = blockIdx.x;
  int b = bp >> 5, p0 = (bp & 31) << 5;
  int t = threadIdx.x;
  int pl = t & 31, cg = t >> 5;
  const float* xp = x + (size_t)b * CDIM * HWD + p0 + pl;
  float s = 0.f;
  for (int cc = 0; cc < 32; ++cc) s += xp[(size_t)(cg * 32 + cc) * HWD];
  red[cg][pl] = s;
  __syncthreads();
  float tot = 0.f;
  for (int g = 0; g < 8; ++g) tot += red[g][pl];
  float mean = tot * (1.f / CDIM);
  __syncthreads();
  float v = 0.f;
  for (int cc = 0; cc < 32; ++cc) {
    float d = xp[(size_t)(cg * 32 + cc) * HWD] - mean;
    v += d * d;
  }
  red[cg][pl] = v;
  __syncthreads();
  if (t < 32) {
    float vv = 0.f;
    for (int g = 0; g < 8; ++g) vv += red[g][t];
    imp[b * 1024 + p0 + t] = vv * (1.f / (CDIM - 1));
  }
}

// ---------------- fused graph pipeline: MFMA GAT ----------------
union GraphLDS {
  struct { float sv[1024]; int si[1024]; } tk;
  struct {
    short h0T[64 * 136];
    short alphaB[102 * 136];
    short gB[102 * 72];
  } m;
};

__global__ __launch_bounds__(1024) void graph_k(
    const float* __restrict__ x, const float* __restrict__ imp,
    const short* __restrict__ w0bT, const short* __restrict__ w1bT,
    const float* __restrict__ g0as, const float* __restrict__ g0ad,
    const float* __restrict__ g0b,
    const float* __restrict__ g1as, const float* __restrict__ g1ad,
    const float* __restrict__ g1b,
    const float* __restrict__ wg2a, const float* __restrict__ bg2a,
    int* __restrict__ nodeof, short* __restrict__ fnG,
    unsigned char* __restrict__ adjG, float* __restrict__ gwb) {
  __shared__ GraphLDS u;
  __shared__ ushort adjPack[NN][8];
  __shared__ float normL[NN];
  __shared__ float asrcL[NN], adstL[NN];
  __shared__ int topiL[NN];
  int b = blockIdx.x, t = threadIdx.x;
  int wv = t >> 6, lane = t & 63, quad = lane >> 4, l16 = lane & 15;

  // ---- phase T: top-102 bitonic sort ----
  u.tk.sv[t] = imp[b * 1024 + t];
  u.tk.si[t] = t;
  nodeof[b * 1024 + t] = -1;
  __syncthreads();
  for (int k = 2; k <= 1024; k <<= 1) {
    for (int j = k >> 1; j > 0; j >>= 1) {
      int ixj = t ^ j;
      if (ixj > t) {
        bool up = ((t & k) == 0);
        float a = u.tk.sv[t], c = u.tk.sv[ixj];
        if ((a > c) == up) {
          u.tk.sv[t] = c; u.tk.sv[ixj] = a;
          int ti = u.tk.si[t]; u.tk.si[t] = u.tk.si[ixj]; u.tk.si[ixj] = ti;
        }
      }
      __syncthreads();
    }
  }
  if (t >= 1024 - NN) {
    int n = 1023 - t;
    int idx = u.tk.si[t];
    topiL[n] = idx;
    nodeof[b * 1024 + idx] = n;
  }
  __syncthreads();

  // ---- phase F: gather -> normalize -> fn bf16 to global; normL ----
  {
    int n = t >> 3, g = t & 7;
    if (n < NN) {
      int idx = topiL[n];
      const float* xb = x + (size_t)b * CDIM * HWD + idx;
      float vbuf[32];
      float ssl = 0.f;
#pragma unroll
      for (int cc = 0; cc < 32; ++cc) {
        float v = xb[(size_t)(g * 32 + cc) * HWD];
        vbuf[cc] = v;
        ssl += v * v;
      }
      ssl += __shfl_xor(ssl, 1);
      ssl += __shfl_xor(ssl, 2);
      ssl += __shfl_xor(ssl, 4);
      float nrm = sqrtf(ssl);
      float rn = 1.f / fmaxf(nrm, 1e-12f);
      if (g == 0) normL[n] = nrm;
      short* fp = fnG + ((size_t)b * 112 + n) * 256 + g * 32;
#pragma unroll
      for (int cc = 0; cc < 32; cc += 4) {
        short4 s4 = {f2bf(vbuf[cc] * rn), f2bf(vbuf[cc + 1] * rn),
                     f2bf(vbuf[cc + 2] * rn), f2bf(vbuf[cc + 3] * rn)};
        *(short4*)(fp + cc) = s4;
      }
    }
  }
  for (int e = t; e < 64 * 34; e += 1024) {
    int f = e / 34, c = 102 + (e % 34);
    u.m.h0T[f * 136 + c] = 0;
  }
  __syncthreads();

  // ---- phase S: cosine sim via MFMA -> adjPack bits + global adj ----
  for (int tile = wv; tile < 49; tile += 16) {
    int I = tile / 7, J = tile % 7;
    const short* ap = fnG + ((size_t)b * 112 + I * 16 + l16) * 256 + quad * 8;
    const short* bp = fnG + ((size_t)b * 112 + J * 16 + l16) * 256 + quad * 8;
    f32x4 acc = (f32x4){0.f, 0.f, 0.f, 0.f};
#pragma unroll
    for (int kb = 0; kb < 8; ++kb)
      acc = __builtin_amdgcn_mfma_f32_16x16x32_bf16(*(const bf16x8*)(ap + kb * 32),
                                                    *(const bf16x8*)(bp + kb * 32), acc, 0, 0, 0);
#pragma unroll
    for (int r = 0; r < 4; ++r) {
      int i = I * 16 + quad * 4 + r, j = J * 16 + l16;
      bool e = (acc[r] > 0.6f) || (i == j);
      unsigned long long m = __ballot(e);
      if (l16 == 0) {
        int row = I * 16 + quad * 4 + r;
        if (row < NN) adjPack[row][J] = (ushort)((m >> (quad * 16)) & 0xFFFFull);
      }
      if (i < NN && j < NN) adjG[(size_t)b * NN * NN + i * NN + j] = e ? 1 : 0;
    }
  }
  __syncthreads();

  // ---- phase G0: h0 = norm * (fn @ W0) -> h0T bf16 ----
  for (int tile = wv; tile < 28; tile += 16) {
    int mt = tile >> 2, nt = tile & 3;
    const short* ap = fnG + ((size_t)b * 112 + mt * 16 + l16) * 256 + quad * 8;
    const short* bp = w0bT + (nt * 16 + l16) * 256 + quad * 8;
    f32x4 acc = (f32x4){0.f, 0.f, 0.f, 0.f};
#pragma unroll
    for (int kb = 0; kb < 8; ++kb)
      acc = __builtin_amdgcn_mfma_f32_16x16x32_bf16(*(const bf16x8*)(ap + kb * 32),
                                                    *(const bf16x8*)(bp + kb * 32), acc, 0, 0, 0);
    int f = nt * 16 + l16;
#pragma unroll
    for (int r = 0; r < 4; ++r) {
      int node = mt * 16 + quad * 4 + r;
      if (node < NN) u.m.h0T[f * 136 + node] = f2bf(acc[r] * normL[node]);
    }
  }
  __syncthreads();

  for (int layer = 0; layer < 2; ++layer) {
    const float* avs = layer ? g1as : g0as;
    const float* avd = layer ? g1ad : g0ad;
    const float* bias = layer ? g1b : g0b;
    {
      int n = t >> 3, g = t & 7;
      if (n < NN) {
        float s1 = 0.f, s2 = 0.f;
#pragma unroll
        for (int uu = 0; uu < 8; ++uu) {
          int f = g * 8 + uu;
          float hv = bf2f(u.m.h0T[f * 136 + n]);
          s1 += hv * avs[f];
          s2 += hv * avd[f];
        }
        s1 += __shfl_xor(s1, 1); s1 += __shfl_xor(s1, 2); s1 += __shfl_xor(s1, 4);
        s2 += __shfl_xor(s2, 1); s2 += __shfl_xor(s2, 2); s2 += __shfl_xor(s2, 4);
        if (g == 0) { asrcL[n] = s1; adstL[n] = s2; }
      }
    }
    __syncthreads();
    for (int i = wv; i < NN; i += 16) {
      float zi = adstL[i];
      int j1 = 64 + lane;
      bool e0 = (adjPack[i][lane >> 4] >> (lane & 15)) & 1;
      bool e1 = (j1 < NN) && ((adjPack[i][j1 >> 4] >> (j1 & 15)) & 1);
      float p0 = 0.f, p1 = 0.f;
      if (e0) { float z = zi + asrcL[lane]; p0 = __expf(z > 0.f ? z : 0.2f * z); }
      if (e1) { float z = zi + asrcL[j1]; p1 = __expf(z > 0.f ? z : 0.2f * z); }
      float s = p0 + p1;
      s += __shfl_xor(s, 1); s += __shfl_xor(s, 2); s += __shfl_xor(s, 4);
      s += __shfl_xor(s, 8); s += __shfl_xor(s, 16); s += __shfl_xor(s, 32);
      float inv = 1.f / s;
      u.m.alphaB[i * 136 + lane] = f2bf(p0 * inv);
      u.m.alphaB[i * 136 + 64 + lane] = f2bf(p1 * inv);
    }
    __syncthreads();
    for (int tile = wv; tile < 28; tile += 16) {
      int mt = tile >> 2, nt = tile & 3;
      int ar = mt * 16 + l16; if (ar > NN - 1) ar = NN - 1;
      const short* ap = &u.m.alphaB[ar * 136 + quad * 8];
      const short* bp = &u.m.h0T[(nt * 16 + l16) * 136 + quad * 8];
      f32x4 acc = (f32x4){0.f, 0.f, 0.f, 0.f};
#pragma unroll
      for (int kb = 0; kb < 4; ++kb)
        acc = __builtin_amdgcn_mfma_f32_16x16x32_bf16(*(const bf16x8*)(ap + kb * 32),
                                                      *(const bf16x8*)(bp + kb * 32), acc, 0, 0, 0);
      int f = nt * 16 + l16;
      float bv = bias[f];
#pragma unroll
      for (int r = 0; r < 4; ++r) {
        int i = mt * 16 + quad * 4 + r;
        if (i < NN) u.m.gB[i * 72 + f] = f2bf(fmaxf(acc[r] + bv, 0.f));
      }
    }
    __syncthreads();
    if (layer == 0) {
      for (int tile = wv; tile < 28; tile += 16) {
        int mt = tile >> 2, nt = tile & 3;
        int ar = mt * 16 + l16; if (ar > NN - 1) ar = NN - 1;
        const short* ap = &u.m.gB[ar * 72 + quad * 8];
        const short* bp = w1bT + (nt * 16 + l16) * 64 + quad * 8;
        f32x4 acc = (f32x4){0.f, 0.f, 0.f, 0.f};
#pragma unroll
        for (int kb = 0; kb < 2; ++kb)
          acc = __builtin_amdgcn_mfma_f32_16x16x32_bf16(*(const bf16x8*)(ap + kb * 32),
                                                        *(const bf16x8*)(bp + kb * 32), acc, 0, 0, 0);
        int f = nt * 16 + l16;
#pragma unroll
        for (int r = 0; r < 4; ++r) {
          int node = mt * 16 + quad * 4 + r;
          if (node < NN) u.m.h0T[f * 136 + node] = f2bf(acc[r]);
        }
      }
      __syncthreads();
    }
  }
  float* wgL = (float*)&u.m.alphaB[0];
  if (t < 512) wgL[t] = wg2a[t];
  __syncthreads();
  if (t < NN * NH) {
    int n = t >> 3, h = t & 7;
    float z = bg2a[h];
#pragma unroll
    for (int c = 0; c < GD; ++c) z += bf2f(u.m.gB[n * 72 + c]) * wgL[h * 64 + c];
    gwb[((size_t)b * NN + n) * NH + h] = 1.f / (1.f + __expf(-z));
  }
}

// ---------------- QKV split-bf16 MFMA GEMM (32-col tiles for occupancy) ----------------
// grid(128, 24): x = M-block of 64 rows; y: qi = y/8 (0=Q,1=K,2=V), n0 = (y%8)*32.
__global__ __launch_bounds__(256, 8) void qkv_k(const short* __restrict__ xth,
                                                const short* __restrict__ xtl,
                                                const short* __restrict__ wqh,
                                                const short* __restrict__ wql,
                                                short* __restrict__ qhp, short* __restrict__ qlp,
                                                short* __restrict__ khp, short* __restrict__ klp,
                                                short* __restrict__ vtp) {
  __shared__ short vs_s[4][32 * 24];
  int t = threadIdx.x, wid = t >> 6, lane = t & 63, quad = lane >> 4, l16 = lane & 15;
  int m0 = blockIdx.x * 64, y = blockIdx.y;
  int b = m0 >> 10;
  int row = m0 + wid * 16 + l16;
  int p_base = (m0 & 1023) + wid * 16;
  int qi = y >> 3, n0 = (y & 7) * 32;
  const short* wh = wqh + ((size_t)qi * 256 + n0) * 256;
  const short* wl = wql + ((size_t)qi * 256 + n0) * 256;
  const short* arh = xth + (size_t)row * 256 + quad * 8;
  const short* arl = xtl + (size_t)row * 256 + quad * 8;
  f32x4 acc[2];
  acc[0] = (f32x4){0.f, 0.f, 0.f, 0.f};
  acc[1] = (f32x4){0.f, 0.f, 0.f, 0.f};
#pragma unroll
  for (int kb = 0; kb < 8; ++kb) {
    bf16x8 ah = *(const bf16x8*)(arh + kb * 32);
    bf16x8 al = *(const bf16x8*)(arl + kb * 32);
#pragma unroll
    for (int nt = 0; nt < 2; ++nt) {
      size_t wo = (size_t)(nt * 16 + l16) * 256 + kb * 32 + quad * 8;
      bf16x8 bh_ = *(const bf16x8*)(wh + wo);
      bf16x8 bl_ = *(const bf16x8*)(wl + wo);
      acc[nt] = __builtin_amdgcn_mfma_f32_16x16x32_bf16(ah, bh_, acc[nt], 0, 0, 0);
      acc[nt] = __builtin_amdgcn_mfma_f32_16x16x32_bf16(ah, bl_, acc[nt], 0, 0, 0);
      acc[nt] = __builtin_amdgcn_mfma_f32_16x16x32_bf16(al, bh_, acc[nt], 0, 0, 0);
    }
  }
  if (qi < 2) {
    const float scale = (qi == 0) ? 0.17677669529663687f : 1.f;
    short* hp = (qi == 0) ? qhp : khp;
    short* lp = (qi == 0) ? qlp : klp;
#pragma unroll
    for (int nt = 0; nt < 2; ++nt) {
      int nq = n0 + nt * 16 + l16;
      int h = nq >> 5, d = nq & 31;
#pragma unroll
      for (int r = 0; r < 4; ++r) {
        int p = p_base + quad * 4 + r;
        float v = acc[nt][r] * scale;
        short hi = f2bf(v);
        short lo = f2bf(v - bf2f(hi));
        size_t e = ((size_t)(b * 8 + h) * 1024 + p) * 32 + d;
        hp[e] = hi;
        lp[e] = lo;
      }
    }
  } else {
    // V: per-wave LDS transpose -> vt[bh][d][p] bf16
    short* vs = &vs_s[wid][0];
#pragma unroll
    for (int nt = 0; nt < 2; ++nt)
#pragma unroll
      for (int r = 0; r < 4; ++r)
        vs[(nt * 16 + l16) * 24 + quad * 4 + r] = f2bf(acc[nt][r]);
    int cl = lane >> 1, hf = lane & 1;
    int nq = n0 + cl;
    int h = nq >> 5, d = nq & 31;
    size_t rb = ((size_t)(b * 8 + h) * 32 + d) * 1024 + p_base + hf * 8;
    *(bf16x8*)(vtp + rb) = *(const bf16x8*)(vs + cl * 24 + hf * 8);
  }
}

// ---------------- flash attention: K-split 2x, XCD-swizzled, deferred-sum, f32 partials ----------------
__global__ __launch_bounds__(256, 8) void attn_k(const short* __restrict__ qh,
                                                 const short* __restrict__ ql,
                                                 const short* __restrict__ kh,
                                                 const short* __restrict__ kl,
                                                 const short* __restrict__ vt,
                                                 const int* __restrict__ nodeof,
                                                 const float* __restrict__ gw,
                                                 const unsigned char* __restrict__ adj,
                                                 float* __restrict__ po,
                                                 float* __restrict__ pl) {
  __shared__ __align__(16) short p_s[4][16 * 72];
  __shared__ float aw_s[4][16];
  int t = threadIdx.x;
  int wid = t >> 6, lane = t & 63, quad = lane >> 4, l16 = lane & 15;
  int bh = blockIdx.x, b = bh >> 3, h = bh & 7;   // bh fastest -> co-XCD q-tiles
  int qt = blockIdx.y, khalf = blockIdx.z;
  int q0 = qt * 64 + wid * 16;
  size_t base = (size_t)bh * 32768;
  short* pw = &p_s[wid][0];
  float* aw = &aw_s[wid][0];

  size_t qoff = base + (size_t)(q0 + l16) * 32 + quad * 8;
  bf16x8 qhf = *(const bf16x8*)(qh + qoff);
  bf16x8 qlf = *(const bf16x8*)(ql + qoff);

  int irow[4]; float grq[4];
#pragma unroll
  for (int r = 0; r < 4; ++r) {
    int qr = q0 + quad * 4 + r;
    int in_ = nodeof[b * 1024 + qr];
    irow[r] = in_;
    grq[r] = (in_ >= 0) ? gw[((size_t)b * NN + in_) * NH + h] : 0.f;
  }
  const unsigned char* adjB = adj + (size_t)b * NN * NN;

  f32x4 ot[2];
  ot[0] = (f32x4){0.f, 0.f, 0.f, 0.f};
  ot[1] = (f32x4){0.f, 0.f, 0.f, 0.f};
  float l_r[4] = {0.f, 0.f, 0.f, 0.f};

  for (int ch = khalf * 8; ch < khalf * 8 + 8; ++ch) {
    int c0 = ch * 64;
    bf16x8 khf[4], klf[4];
#pragma unroll
    for (int ni = 0; ni < 4; ++ni) {
      size_t off = base + (size_t)(c0 + ni * 16 + l16) * 32 + quad * 8;
      khf[ni] = *(const bf16x8*)(kh + off);
      klf[ni] = *(const bf16x8*)(kl + off);
    }
    bf16x8 vaf[2][2];
#pragma unroll
    for (int mi = 0; mi < 2; ++mi)
#pragma unroll
      for (int ks = 0; ks < 2; ++ks)
        vaf[mi][ks] = *(const bf16x8*)(vt + base + (size_t)(mi * 16 + l16) * 1024 +
                                       c0 + ks * 32 + quad * 8);
    int jn[4]; float gcn[4];
#pragma unroll
    for (int ni = 0; ni < 4; ++ni) {
      int j = nodeof[b * 1024 + c0 + ni * 16 + l16];
      jn[ni] = j;
      gcn[ni] = (j >= 0) ? gw[((size_t)b * NN + j) * NH + h] : 0.f;
    }
    f32x4 s[4];
#pragma unroll
    for (int ni = 0; ni < 4; ++ni) {
      f32x4 a = (f32x4){0.f, 0.f, 0.f, 0.f};
      a = __builtin_amdgcn_mfma_f32_16x16x32_bf16(qhf, khf[ni], a, 0, 0, 0);
      a = __builtin_amdgcn_mfma_f32_16x16x32_bf16(qhf, klf[ni], a, 0, 0, 0);
      a = __builtin_amdgcn_mfma_f32_16x16x32_bf16(qlf, khf[ni], a, 0, 0, 0);
      s[ni] = a;
    }
#pragma unroll
    for (int r = 0; r < 4; ++r) {
      int in_ = irow[r];
      if (in_ >= 0) {
        const unsigned char* ar = adjB + (size_t)in_ * NN;
        float g = grq[r];
#pragma unroll
        for (int ni = 0; ni < 4; ++ni)
          if (jn[ni] >= 0 && ar[jn[ni]]) s[ni][r] += g * gcn[ni];
      }
    }
#pragma unroll
    for (int r = 0; r < 4; ++r) {
      float e0 = __expf(s[0][r]);
      float e1 = __expf(s[1][r]);
      float e2 = __expf(s[2][r]);
      float e3 = __expf(s[3][r]);
      l_r[r] += (e0 + e1) + (e2 + e3);
      int prow = (quad * 4 + r) * 72;
      pw[prow + 0 + l16] = f2bf(e0);
      pw[prow + 16 + l16] = f2bf(e1);
      pw[prow + 32 + l16] = f2bf(e2);
      pw[prow + 48 + l16] = f2bf(e3);
    }
#pragma unroll
    for (int ks = 0; ks < 2; ++ks) {
      bf16x8 pb = *(const bf16x8*)(pw + l16 * 72 + ks * 32 + quad * 8);
      ot[0] = __builtin_amdgcn_mfma_f32_16x16x32_bf16(vaf[0][ks], pb, ot[0], 0, 0, 0);
      ot[1] = __builtin_amdgcn_mfma_f32_16x16x32_bf16(vaf[1][ks], pb, ot[1], 0, 0, 0);
    }
  }
  // partial row-sums + raw partial O (normalization deferred to reduce_k)
#pragma unroll
  for (int r = 0; r < 4; ++r) {
    float ls = l_r[r];
    ls += __shfl_xor(ls, 1);
    ls += __shfl_xor(ls, 2);
    ls += __shfl_xor(ls, 4);
    ls += __shfl_xor(ls, 8);
    if (l16 == 0) aw[quad * 4 + r] = ls;
  }
  float* os = (float*)pw;
#pragma unroll
  for (int mi = 0; mi < 2; ++mi)
#pragma unroll
    for (int r = 0; r < 4; ++r)
      os[l16 * 36 + mi * 16 + quad * 4 + r] = ot[mi][r];
  int bht = bh * 16 + qt;
  size_t pob = (((size_t)bht * 2 + khalf) * 64 + wid * 16) * 32;
  int qr2 = lane >> 2, dg = (lane & 3) * 8;
  *(float4*)&po[pob + qr2 * 32 + dg] = *(float4*)&os[qr2 * 36 + dg];
  *(float4*)&po[pob + qr2 * 32 + dg + 4] = *(float4*)&os[qr2 * 36 + dg + 4];
  if (lane < 16) pl[((size_t)bht * 2 + khalf) * 64 + wid * 16 + lane] = aw[lane];
}

// ---------------- combine K-split halves, normalize, emit hi/lo bf16 ao ----------------
__global__ __launch_bounds__(256) void reduce_k(const float* __restrict__ po,
                                                const float* __restrict__ pl,
                                                short* __restrict__ aoh,
                                                short* __restrict__ aol) {
  int bht = blockIdx.x;                 // 1024
  int bh = bht >> 4, qt = bht & 15;
  int b = bh >> 3, h = bh & 7;
  int t = threadIdx.x;
  int q = t >> 2, dg = (t & 3) * 8;
  size_t b0 = (((size_t)bht * 2 + 0) * 64 + q) * 32 + dg;
  size_t b1 = (((size_t)bht * 2 + 1) * 64 + q) * 32 + dg;
  float4 a0 = *(const float4*)&po[b0];
  float4 a1 = *(const float4*)&po[b0 + 4];
  float4 c0 = *(const float4*)&po[b1];
  float4 c1 = *(const float4*)&po[b1 + 4];
  float l = pl[((size_t)bht * 2) * 64 + q] + pl[((size_t)bht * 2 + 1) * 64 + q];
  float inv = 1.f / l;
  float f[8] = {(a0.x + c0.x) * inv, (a0.y + c0.y) * inv,
                (a0.z + c0.z) * inv, (a0.w + c0.w) * inv,
                (a1.x + c1.x) * inv, (a1.y + c1.y) * inv,
                (a1.z + c1.z) * inv, (a1.w + c1.w) * inv};
  bf16x8 hv, lv;
#pragma unroll
  for (int j = 0; j < 8; ++j) {
    hv[j] = f2bf(f[j]);
    lv[j] = f2bf(f[j] - bf2f(hv[j]));
  }
  size_t ob = (size_t)(b * 1024 + qt * 64 + q) * 256 + h * 32 + dg;
  *(bf16x8*)(aoh + ob) = hv;
  *(bf16x8*)(aol + ob) = lv;
}

// ---------------- proj split-bf16 MFMA GEMM (32-col tiles) + bias + transposed store ----------------
__global__ __launch_bounds__(256, 8) void proj_k(const short* __restrict__ aoh,
                                                 const short* __restrict__ aol,
                                                 const short* __restrict__ wph,
                                                 const short* __restrict__ wpl,
                                                 const float* __restrict__ bias,
                                                 float* __restrict__ out) {
  __shared__ float os_s[4][32 * 20];
  int t = threadIdx.x, wid = t >> 6, lane = t & 63, quad = lane >> 4, l16 = lane & 15;
  int m0 = blockIdx.x * 64, n0 = blockIdx.y * 32;
  int b = m0 >> 10;
  int row = m0 + wid * 16 + l16;
  int p_base = (m0 & 1023) + wid * 16;
  const short* arh = aoh + (size_t)row * 256 + quad * 8;
  const short* arl = aol + (size_t)row * 256 + quad * 8;
  f32x4 acc[2];
  acc[0] = (f32x4){0.f, 0.f, 0.f, 0.f};
  acc[1] = (f32x4){0.f, 0.f, 0.f, 0.f};
#pragma unroll
  for (int kb = 0; kb < 8; ++kb) {
    bf16x8 ah = *(const bf16x8*)(arh + kb * 32);
    bf16x8 al = *(const bf16x8*)(arl + kb * 32);
#pragma unroll
    for (int nt = 0; nt < 2; ++nt) {
      size_t wo = (size_t)(n0 + nt * 16 + l16) * 256 + kb * 32 + quad * 8;
      bf16x8 bh_ = *(const bf16x8*)(wph + wo);
      bf16x8 bl_ = *(const bf16x8*)(wpl + wo);
      acc[nt] = __builtin_amdgcn_mfma_f32_16x16x32_bf16(ah, bh_, acc[nt], 0, 0, 0);
      acc[nt] = __builtin_amdgcn_mfma_f32_16x16x32_bf16(ah, bl_, acc[nt], 0, 0, 0);
      acc[nt] = __builtin_amdgcn_mfma_f32_16x16x32_bf16(al, bh_, acc[nt], 0, 0, 0);
    }
  }
  float* os = &os_s[wid][0];
#pragma unroll
  for (int nt = 0; nt < 2; ++nt) {
    float bv = bias[n0 + nt * 16 + l16];
#pragma unroll
    for (int r = 0; r < 4; ++r)
      os[(nt * 16 + l16) * 20 + quad * 4 + r] = acc[nt][r] + bv;
  }
  int cl = lane >> 1, hf = lane & 1;
  int c = n0 + cl;
  float* orow = out + ((size_t)(b * 256 + c)) * 1024 + p_base;
  *(float4*)(orow + hf * 8) = *(float4*)&os[cl * 20 + hf * 8];
  *(float4*)(orow + hf * 8 + 4) = *(float4*)&os[cl * 20 + hf * 8 + 4];
}

extern "C" void kernel_launch(void* const* d_in, const int* in_sizes, int n_in,
                              void* d_out, int out_size, void* d_ws, size_t ws_size,
                              hipStream_t stream) {
  const float* x      = (const float*)d_in[0];
  const float* w_qkv  = (const float*)d_in[1];
  const float* w_proj = (const float*)d_in[2];
  const float* b_proj = (const float*)d_in[3];
  const float* g0W    = (const float*)d_in[4];
  const float* g0as   = (const float*)d_in[5];
  const float* g0ad   = (const float*)d_in[6];
  const float* g0b    = (const float*)d_in[7];
  const float* g1W    = (const float*)d_in[8];
  const float* g1as   = (const float*)d_in[9];
  const float* g1ad   = (const float*)d_in[10];
  const float* g1b    = (const float*)d_in[11];
  const float* wg2a   = (const float*)d_in[12];
  const float* bg2a   = (const float*)d_in[13];
  float* out = (float*)d_out;
  float* ws = (float*)d_ws;

  size_t o = 0;
  auto alloc = [&](size_t nf) { float* p = ws + o; o += (nf + 15) & ~(size_t)15; return p; };
  float* imp    = alloc(8 * 1024);
  int*   nodeof = (int*)alloc(8 * 1024);
  short* fnG    = (short*)alloc(8 * 112 * 256 / 2);
  short* w0bT   = (short*)alloc(256 * 64 / 2);
  short* w1bT   = (short*)alloc(64 * 64 / 2);
  unsigned char* adj = (unsigned char*)alloc((8 * NN * NN + 3) / 4 + 16);
  float* gwb    = alloc(8 * NN * 8);
  short* xth    = (short*)alloc(1048576);
  short* xtl    = (short*)alloc(1048576);
  short* wqh    = (short*)alloc(98304);
  short* wql    = (short*)alloc(98304);
  short* wph    = (short*)alloc(32768);
  short* wpl    = (short*)alloc(32768);
  short* qh     = (short*)alloc(1048576);
  short* ql     = (short*)alloc(1048576);
  short* kh     = (short*)alloc(1048576);
  short* kl     = (short*)alloc(1048576);
  short* vt     = (short*)alloc(1048576);
  short* aoh    = (short*)alloc(1048576);
  short* aol    = (short*)alloc(1048576);
  float* po     = alloc((size_t)1024 * 2 * 64 * 32);
  float* plv    = alloc((size_t)1024 * 2 * 64);
  if (ws_size < o * sizeof(float)) return;

  importance_k<<<256, 256, 0, stream>>>(x, imp);
  wsplit_k<<<1024, 256, 0, stream>>>(w_qkv, w_proj, wqh, wql, wph, wpl);
  xsplit_k<<<dim3(16, 4, 8), 256, 0, stream>>>(x, xth, xtl);
  prep_k<<<80, 256, 0, stream>>>(g0W, g1W, w0bT, w1bT);
  graph_k<<<8, 1024, 0, stream>>>(x, imp, w0bT, w1bT, g0as, g0ad, g0b,
                                  g1as, g1ad, g1b, wg2a, bg2a,
                                  nodeof, fnG, adj, gwb);
  qkv_k<<<dim3(128, 24), 256, 0, stream>>>(xth, xtl, wqh, wql, qh, ql, kh, kl, vt);
  attn_k<<<dim3(64, 16, 2), 256, 0, stream>>>(qh, ql, kh, kl, vt, nodeof, gwb, adj, po, plv);
  reduce_k<<<1024, 256, 0, stream>>>(po, plv, aoh, aol);
  proj_k<<<dim3(128, 8), 256, 0, stream>>>(aoh, aol, wph, wpl, b_proj, out);
}

// Round 7
// 369.070 us; speedup vs baseline: 1.2590x; 1.2590x over previous
//
#include <hip/hip_runtime.h>
#include <math.h>

#define NB 8
#define CDIM 256
#define HWD 1024
#define NH 8
#define HD 32
#define NN 102
#define GD 64

typedef __attribute__((ext_vector_type(8))) short bf16x8;
typedef __attribute__((ext_vector_type(4))) float f32x4;

__device__ inline short f2bf(float f) {
  union { float f; unsigned u; } v; v.f = f;
  unsigned r = v.u + 0x7fffu + ((v.u >> 16) & 1u);
  return (short)(r >> 16);
}
__device__ inline float bf2f(short s) {
  union { unsigned u; float f; } v;
  v.u = ((unsigned)(unsigned short)s) << 16;
  return v.f;
}

// ---------------- split weights into hi/lo bf16 ([n][k] layout kept) ----------------
__global__ __launch_bounds__(256) void wsplit_k(const float* __restrict__ w_qkv,
                                                const float* __restrict__ w_proj,
                                                short* __restrict__ wqh, short* __restrict__ wql,
                                                short* __restrict__ wph, short* __restrict__ wpl) {
  int t = blockIdx.x * 256 + threadIdx.x;
  if (t < 196608) {
    float v = w_qkv[t];
    short hi = f2bf(v);
    wqh[t] = hi; wql[t] = f2bf(v - bf2f(hi));
  } else {
    int u = t - 196608;
    float v = w_proj[u];
    short hi = f2bf(v);
    wph[u] = hi; wpl[u] = f2bf(v - bf2f(hi));
  }
}

// ---------------- x [b][c][p] -> xt hi/lo bf16 [b][p][c] ----------------
__global__ __launch_bounds__(256) void xsplit_k(const float* __restrict__ x,
                                                short* __restrict__ xth,
                                                short* __restrict__ xtl) {
  __shared__ float tile[64][65];
  int p0 = blockIdx.x * 64, c0 = blockIdx.y * 64, b = blockIdx.z;
  int t = threadIdx.x;
  {
    int g = t >> 6, p = t & 63;
#pragma unroll
    for (int i = 0; i < 16; ++i) {
      int cc = g * 16 + i;
      tile[cc][p] = x[((size_t)(b * 256 + c0 + cc)) * 1024 + p0 + p];
    }
  }
  __syncthreads();
  {
    int p = t >> 2, cs = (t & 3) * 16;
    size_t rb = ((size_t)(b * 1024 + p0 + p)) * 256 + c0 + cs;
#pragma unroll
    for (int g = 0; g < 4; ++g) {
      short4 hv, lv;
      float f0 = tile[cs + g * 4 + 0][p];
      float f1 = tile[cs + g * 4 + 1][p];
      float f2 = tile[cs + g * 4 + 2][p];
      float f3 = tile[cs + g * 4 + 3][p];
      hv.x = f2bf(f0); lv.x = f2bf(f0 - bf2f(hv.x));
      hv.y = f2bf(f1); lv.y = f2bf(f1 - bf2f(hv.y));
      hv.z = f2bf(f2); lv.z = f2bf(f2 - bf2f(hv.z));
      hv.w = f2bf(f3); lv.w = f2bf(f3 - bf2f(hv.w));
      *(short4*)(xth + rb + g * 4) = hv;
      *(short4*)(xtl + rb + g * 4) = lv;
    }
  }
}

// ---------------- prep: bf16-transposed GAT weights ----------------
__global__ __launch_bounds__(256) void prep_k(const float* __restrict__ g0W,
                                              const float* __restrict__ g1W,
                                              short* __restrict__ w0bT,
                                              short* __restrict__ w1bT) {
  int t = blockIdx.x * 256 + threadIdx.x;
  if (t < 16384) {
    int c = t >> 6, f = t & 63;
    w0bT[f * 256 + c] = f2bf(g0W[t]);
  } else if (t < 20480) {
    int u2 = t - 16384;
    int c = u2 >> 6, f = u2 & 63;
    w1bT[f * 64 + c] = f2bf(g1W[u2]);
  }
}

// ---------------- importance = unbiased variance over channels ----------------
__global__ __launch_bounds__(256) void importance_k(const float* __restrict__ x,
                                                    float* __restrict__ imp) {
  __shared__ float red[8][33];
  int bp = blockIdx.x;
  int b = bp >> 5, p0 = (bp & 31) << 5;
  int t = threadIdx.x;
  int pl = t & 31, cg = t >> 5;
  const float* xp = x + (size_t)b * CDIM * HWD + p0 + pl;
  float s = 0.f;
  for (int cc = 0; cc < 32; ++cc) s += xp[(size_t)(cg * 32 + cc) * HWD];
  red[cg][pl] = s;
  __syncthreads();
  float tot = 0.f;
  for (int g = 0; g < 8; ++g) tot += red[g][pl];
  float mean = tot * (1.f / CDIM);
  __syncthreads();
  float v = 0.f;
  for (int cc = 0; cc < 32; ++cc) {
    float d = xp[(size_t)(cg * 32 + cc) * HWD] - mean;
    v += d * d;
  }
  red[cg][pl] = v;
  __syncthreads();
  if (t < 32) {
    float vv = 0.f;
    for (int g = 0; g < 8; ++g) vv += red[g][t];
    imp[b * 1024 + p0 + t] = vv * (1.f / (CDIM - 1));
  }
}

// ---------------- fused graph pipeline: MFMA GAT ----------------
union GraphLDS {
  struct { float sv[1024]; int si[1024]; } tk;
  struct {
    short h0T[64 * 136];
    short alphaB[102 * 136];
    short gB[102 * 72];
  } m;
};

__global__ __launch_bounds__(1024) void graph_k(
    const float* __restrict__ x, const float* __restrict__ imp,
    const short* __restrict__ w0bT, const short* __restrict__ w1bT,
    const float* __restrict__ g0as, const float* __restrict__ g0ad,
    const float* __restrict__ g0b,
    const float* __restrict__ g1as, const float* __restrict__ g1ad,
    const float* __restrict__ g1b,
    const float* __restrict__ wg2a, const float* __restrict__ bg2a,
    int* __restrict__ nodeof, short* __restrict__ fnG,
    unsigned char* __restrict__ adjG, float* __restrict__ gwb) {
  __shared__ GraphLDS u;
  __shared__ ushort adjPack[NN][8];
  __shared__ float normL[NN];
  __shared__ float asrcL[NN], adstL[NN];
  __shared__ int topiL[NN];
  int b = blockIdx.x, t = threadIdx.x;
  int wv = t >> 6, lane = t & 63, quad = lane >> 4, l16 = lane & 15;

  // ---- phase T: top-102 bitonic sort ----
  u.tk.sv[t] = imp[b * 1024 + t];
  u.tk.si[t] = t;
  nodeof[b * 1024 + t] = -1;
  __syncthreads();
  for (int k = 2; k <= 1024; k <<= 1) {
    for (int j = k >> 1; j > 0; j >>= 1) {
      int ixj = t ^ j;
      if (ixj > t) {
        bool up = ((t & k) == 0);
        float a = u.tk.sv[t], c = u.tk.sv[ixj];
        if ((a > c) == up) {
          u.tk.sv[t] = c; u.tk.sv[ixj] = a;
          int ti = u.tk.si[t]; u.tk.si[t] = u.tk.si[ixj]; u.tk.si[ixj] = ti;
        }
      }
      __syncthreads();
    }
  }
  if (t >= 1024 - NN) {
    int n = 1023 - t;
    int idx = u.tk.si[t];
    topiL[n] = idx;
    nodeof[b * 1024 + idx] = n;
  }
  __syncthreads();

  // ---- phase F: gather -> normalize -> fn bf16 to global; normL ----
  {
    int n = t >> 3, g = t & 7;
    if (n < NN) {
      int idx = topiL[n];
      const float* xb = x + (size_t)b * CDIM * HWD + idx;
      float vbuf[32];
      float ssl = 0.f;
#pragma unroll
      for (int cc = 0; cc < 32; ++cc) {
        float v = xb[(size_t)(g * 32 + cc) * HWD];
        vbuf[cc] = v;
        ssl += v * v;
      }
      ssl += __shfl_xor(ssl, 1);
      ssl += __shfl_xor(ssl, 2);
      ssl += __shfl_xor(ssl, 4);
      float nrm = sqrtf(ssl);
      float rn = 1.f / fmaxf(nrm, 1e-12f);
      if (g == 0) normL[n] = nrm;
      short* fp = fnG + ((size_t)b * 112 + n) * 256 + g * 32;
#pragma unroll
      for (int cc = 0; cc < 32; cc += 4) {
        short4 s4 = {f2bf(vbuf[cc] * rn), f2bf(vbuf[cc + 1] * rn),
                     f2bf(vbuf[cc + 2] * rn), f2bf(vbuf[cc + 3] * rn)};
        *(short4*)(fp + cc) = s4;
      }
    }
  }
  for (int e = t; e < 64 * 34; e += 1024) {
    int f = e / 34, c = 102 + (e % 34);
    u.m.h0T[f * 136 + c] = 0;
  }
  __syncthreads();

  // ---- phase S: cosine sim via MFMA -> adjPack bits + global adj ----
  for (int tile = wv; tile < 49; tile += 16) {
    int I = tile / 7, J = tile % 7;
    const short* ap = fnG + ((size_t)b * 112 + I * 16 + l16) * 256 + quad * 8;
    const short* bp = fnG + ((size_t)b * 112 + J * 16 + l16) * 256 + quad * 8;
    f32x4 acc = (f32x4){0.f, 0.f, 0.f, 0.f};
#pragma unroll
    for (int kb = 0; kb < 8; ++kb)
      acc = __builtin_amdgcn_mfma_f32_16x16x32_bf16(*(const bf16x8*)(ap + kb * 32),
                                                    *(const bf16x8*)(bp + kb * 32), acc, 0, 0, 0);
#pragma unroll
    for (int r = 0; r < 4; ++r) {
      int i = I * 16 + quad * 4 + r, j = J * 16 + l16;
      bool e = (acc[r] > 0.6f) || (i == j);
      unsigned long long m = __ballot(e);
      if (l16 == 0) {
        int row = I * 16 + quad * 4 + r;
        if (row < NN) adjPack[row][J] = (ushort)((m >> (quad * 16)) & 0xFFFFull);
      }
      if (i < NN && j < NN) adjG[(size_t)b * NN * NN + i * NN + j] = e ? 1 : 0;
    }
  }
  __syncthreads();

  // ---- phase G0: h0 = norm * (fn @ W0) -> h0T bf16 ----
  for (int tile = wv; tile < 28; tile += 16) {
    int mt = tile >> 2, nt = tile & 3;
    const short* ap = fnG + ((size_t)b * 112 + mt * 16 + l16) * 256 + quad * 8;
    const short* bp = w0bT + (nt * 16 + l16) * 256 + quad * 8;
    f32x4 acc = (f32x4){0.f, 0.f, 0.f, 0.f};
#pragma unroll
    for (int kb = 0; kb < 8; ++kb)
      acc = __builtin_amdgcn_mfma_f32_16x16x32_bf16(*(const bf16x8*)(ap + kb * 32),
                                                    *(const bf16x8*)(bp + kb * 32), acc, 0, 0, 0);
    int f = nt * 16 + l16;
#pragma unroll
    for (int r = 0; r < 4; ++r) {
      int node = mt * 16 + quad * 4 + r;
      if (node < NN) u.m.h0T[f * 136 + node] = f2bf(acc[r] * normL[node]);
    }
  }
  __syncthreads();

  for (int layer = 0; layer < 2; ++layer) {
    const float* avs = layer ? g1as : g0as;
    const float* avd = layer ? g1ad : g0ad;
    const float* bias = layer ? g1b : g0b;
    {
      int n = t >> 3, g = t & 7;
      if (n < NN) {
        float s1 = 0.f, s2 = 0.f;
#pragma unroll
        for (int uu = 0; uu < 8; ++uu) {
          int f = g * 8 + uu;
          float hv = bf2f(u.m.h0T[f * 136 + n]);
          s1 += hv * avs[f];
          s2 += hv * avd[f];
        }
        s1 += __shfl_xor(s1, 1); s1 += __shfl_xor(s1, 2); s1 += __shfl_xor(s1, 4);
        s2 += __shfl_xor(s2, 1); s2 += __shfl_xor(s2, 2); s2 += __shfl_xor(s2, 4);
        if (g == 0) { asrcL[n] = s1; adstL[n] = s2; }
      }
    }
    __syncthreads();
    for (int i = wv; i < NN; i += 16) {
      float zi = adstL[i];
      int j1 = 64 + lane;
      bool e0 = (adjPack[i][lane >> 4] >> (lane & 15)) & 1;
      bool e1 = (j1 < NN) && ((adjPack[i][j1 >> 4] >> (j1 & 15)) & 1);
      float p0 = 0.f, p1 = 0.f;
      if (e0) { float z = zi + asrcL[lane]; p0 = __expf(z > 0.f ? z : 0.2f * z); }
      if (e1) { float z = zi + asrcL[j1]; p1 = __expf(z > 0.f ? z : 0.2f * z); }
      float s = p0 + p1;
      s += __shfl_xor(s, 1); s += __shfl_xor(s, 2); s += __shfl_xor(s, 4);
      s += __shfl_xor(s, 8); s += __shfl_xor(s, 16); s += __shfl_xor(s, 32);
      float inv = 1.f / s;
      u.m.alphaB[i * 136 + lane] = f2bf(p0 * inv);
      u.m.alphaB[i * 136 + 64 + lane] = f2bf(p1 * inv);
    }
    __syncthreads();
    for (int tile = wv; tile < 28; tile += 16) {
      int mt = tile >> 2, nt = tile & 3;
      int ar = mt * 16 + l16; if (ar > NN - 1) ar = NN - 1;
      const short* ap = &u.m.alphaB[ar * 136 + quad * 8];
      const short* bp = &u.m.h0T[(nt * 16 + l16) * 136 + quad * 8];
      f32x4 acc = (f32x4){0.f, 0.f, 0.f, 0.f};
#pragma unroll
      for (int kb = 0; kb < 4; ++kb)
        acc = __builtin_amdgcn_mfma_f32_16x16x32_bf16(*(const bf16x8*)(ap + kb * 32),
                                                      *(const bf16x8*)(bp + kb * 32), acc, 0, 0, 0);
      int f = nt * 16 + l16;
      float bv = bias[f];
#pragma unroll
      for (int r = 0; r < 4; ++r) {
        int i = mt * 16 + quad * 4 + r;
        if (i < NN) u.m.gB[i * 72 + f] = f2bf(fmaxf(acc[r] + bv, 0.f));
      }
    }
    __syncthreads();
    if (layer == 0) {
      for (int tile = wv; tile < 28; tile += 16) {
        int mt = tile >> 2, nt = tile & 3;
        int ar = mt * 16 + l16; if (ar > NN - 1) ar = NN - 1;
        const short* ap = &u.m.gB[ar * 72 + quad * 8];
        const short* bp = w1bT + (nt * 16 + l16) * 64 + quad * 8;
        f32x4 acc = (f32x4){0.f, 0.f, 0.f, 0.f};
#pragma unroll
        for (int kb = 0; kb < 2; ++kb)
          acc = __builtin_amdgcn_mfma_f32_16x16x32_bf16(*(const bf16x8*)(ap + kb * 32),
                                                        *(const bf16x8*)(bp + kb * 32), acc, 0, 0, 0);
        int f = nt * 16 + l16;
#pragma unroll
        for (int r = 0; r < 4; ++r) {
          int node = mt * 16 + quad * 4 + r;
          if (node < NN) u.m.h0T[f * 136 + node] = f2bf(acc[r]);
        }
      }
      __syncthreads();
    }
  }
  float* wgL = (float*)&u.m.alphaB[0];
  if (t < 512) wgL[t] = wg2a[t];
  __syncthreads();
  if (t < NN * NH) {
    int n = t >> 3, h = t & 7;
    float z = bg2a[h];
#pragma unroll
    for (int c = 0; c < GD; ++c) z += bf2f(u.m.gB[n * 72 + c]) * wgL[h * 64 + c];
    gwb[((size_t)b * NN + n) * NH + h] = 1.f / (1.f + __expf(-z));
  }
}

// ---------------- QKV split-bf16 MFMA GEMM (32-col tiles) ----------------
// grid(128, 24): x = M-block of 64 rows; y: qi = y/8 (0=Q,1=K,2=V), n0 = (y%8)*32.
__global__ __launch_bounds__(256, 4) void qkv_k(const short* __restrict__ xth,
                                                const short* __restrict__ xtl,
                                                const short* __restrict__ wqh,
                                                const short* __restrict__ wql,
                                                short* __restrict__ qhp, short* __restrict__ qlp,
                                                short* __restrict__ khp, short* __restrict__ klp,
                                                short* __restrict__ vtp) {
  __shared__ short vs_s[4][32 * 24];
  int t = threadIdx.x, wid = t >> 6, lane = t & 63, quad = lane >> 4, l16 = lane & 15;
  int m0 = blockIdx.x * 64, y = blockIdx.y;
  int b = m0 >> 10;
  int row = m0 + wid * 16 + l16;
  int p_base = (m0 & 1023) + wid * 16;
  int qi = y >> 3, n0 = (y & 7) * 32;
  const short* wh = wqh + ((size_t)qi * 256 + n0) * 256;
  const short* wl = wql + ((size_t)qi * 256 + n0) * 256;
  const short* arh = xth + (size_t)row * 256 + quad * 8;
  const short* arl = xtl + (size_t)row * 256 + quad * 8;
  f32x4 acc[2];
  acc[0] = (f32x4){0.f, 0.f, 0.f, 0.f};
  acc[1] = (f32x4){0.f, 0.f, 0.f, 0.f};
#pragma unroll
  for (int kb = 0; kb < 8; ++kb) {
    bf16x8 ah = *(const bf16x8*)(arh + kb * 32);
    bf16x8 al = *(const bf16x8*)(arl + kb * 32);
#pragma unroll
    for (int nt = 0; nt < 2; ++nt) {
      size_t wo = (size_t)(nt * 16 + l16) * 256 + kb * 32 + quad * 8;
      bf16x8 bh_ = *(const bf16x8*)(wh + wo);
      bf16x8 bl_ = *(const bf16x8*)(wl + wo);
      acc[nt] = __builtin_amdgcn_mfma_f32_16x16x32_bf16(ah, bh_, acc[nt], 0, 0, 0);
      acc[nt] = __builtin_amdgcn_mfma_f32_16x16x32_bf16(ah, bl_, acc[nt], 0, 0, 0);
      acc[nt] = __builtin_amdgcn_mfma_f32_16x16x32_bf16(al, bh_, acc[nt], 0, 0, 0);
    }
  }
  if (qi < 2) {
    const float scale = (qi == 0) ? 0.17677669529663687f : 1.f;
    short* hp = (qi == 0) ? qhp : khp;
    short* lp = (qi == 0) ? qlp : klp;
#pragma unroll
    for (int nt = 0; nt < 2; ++nt) {
      int nq = n0 + nt * 16 + l16;
      int h = nq >> 5, d = nq & 31;
#pragma unroll
      for (int r = 0; r < 4; ++r) {
        int p = p_base + quad * 4 + r;
        float v = acc[nt][r] * scale;
        short hi = f2bf(v);
        short lo = f2bf(v - bf2f(hi));
        size_t e = ((size_t)(b * 8 + h) * 1024 + p) * 32 + d;
        hp[e] = hi;
        lp[e] = lo;
      }
    }
  } else {
    // V: per-wave LDS transpose -> vt[bh][d][p] bf16
    short* vs = &vs_s[wid][0];
#pragma unroll
    for (int nt = 0; nt < 2; ++nt)
#pragma unroll
      for (int r = 0; r < 4; ++r)
        vs[(nt * 16 + l16) * 24 + quad * 4 + r] = f2bf(acc[nt][r]);
    int cl = lane >> 1, hf = lane & 1;
    int nq = n0 + cl;
    int h = nq >> 5, d = nq & 31;
    size_t rb = ((size_t)(b * 8 + h) * 32 + d) * 1024 + p_base + hf * 8;
    *(bf16x8*)(vtp + rb) = *(const bf16x8*)(vs + cl * 24 + hf * 8);
  }
}

// ---------------- flash attention: K-split 2x, XCD-swizzled, deferred-sum, f32 partials ----------------
__global__ __launch_bounds__(256, 4) void attn_k(const short* __restrict__ qh,
                                                 const short* __restrict__ ql,
                                                 const short* __restrict__ kh,
                                                 const short* __restrict__ kl,
                                                 const short* __restrict__ vt,
                                                 const int* __restrict__ nodeof,
                                                 const float* __restrict__ gw,
                                                 const unsigned char* __restrict__ adj,
                                                 float* __restrict__ po,
                                                 float* __restrict__ pl) {
  __shared__ __align__(16) short p_s[4][16 * 72];
  __shared__ float aw_s[4][16];
  int t = threadIdx.x;
  int wid = t >> 6, lane = t & 63, quad = lane >> 4, l16 = lane & 15;
  int bh = blockIdx.x, b = bh >> 3, h = bh & 7;   // bh fastest -> co-XCD q-tiles
  int qt = blockIdx.y, khalf = blockIdx.z;
  int q0 = qt * 64 + wid * 16;
  size_t base = (size_t)bh * 32768;
  short* pw = &p_s[wid][0];
  float* aw = &aw_s[wid][0];

  size_t qoff = base + (size_t)(q0 + l16) * 32 + quad * 8;
  bf16x8 qhf = *(const bf16x8*)(qh + qoff);
  bf16x8 qlf = *(const bf16x8*)(ql + qoff);

  int irow[4]; float grq[4];
#pragma unroll
  for (int r = 0; r < 4; ++r) {
    int qr = q0 + quad * 4 + r;
    int in_ = nodeof[b * 1024 + qr];
    irow[r] = in_;
    grq[r] = (in_ >= 0) ? gw[((size_t)b * NN + in_) * NH + h] : 0.f;
  }
  const unsigned char* adjB = adj + (size_t)b * NN * NN;

  f32x4 ot[2];
  ot[0] = (f32x4){0.f, 0.f, 0.f, 0.f};
  ot[1] = (f32x4){0.f, 0.f, 0.f, 0.f};
  float l_r[4] = {0.f, 0.f, 0.f, 0.f};

  for (int ch = khalf * 8; ch < khalf * 8 + 8; ++ch) {
    int c0 = ch * 64;
    bf16x8 khf[4], klf[4];
#pragma unroll
    for (int ni = 0; ni < 4; ++ni) {
      size_t off = base + (size_t)(c0 + ni * 16 + l16) * 32 + quad * 8;
      khf[ni] = *(const bf16x8*)(kh + off);
      klf[ni] = *(const bf16x8*)(kl + off);
    }
    bf16x8 vaf[2][2];
#pragma unroll
    for (int mi = 0; mi < 2; ++mi)
#pragma unroll
      for (int ks = 0; ks < 2; ++ks)
        vaf[mi][ks] = *(const bf16x8*)(vt + base + (size_t)(mi * 16 + l16) * 1024 +
                                       c0 + ks * 32 + quad * 8);
    int jn[4]; float gcn[4];
#pragma unroll
    for (int ni = 0; ni < 4; ++ni) {
      int j = nodeof[b * 1024 + c0 + ni * 16 + l16];
      jn[ni] = j;
      gcn[ni] = (j >= 0) ? gw[((size_t)b * NN + j) * NH + h] : 0.f;
    }
    f32x4 s[4];
#pragma unroll
    for (int ni = 0; ni < 4; ++ni) {
      f32x4 a = (f32x4){0.f, 0.f, 0.f, 0.f};
      a = __builtin_amdgcn_mfma_f32_16x16x32_bf16(qhf, khf[ni], a, 0, 0, 0);
      a = __builtin_amdgcn_mfma_f32_16x16x32_bf16(qhf, klf[ni], a, 0, 0, 0);
      a = __builtin_amdgcn_mfma_f32_16x16x32_bf16(qlf, khf[ni], a, 0, 0, 0);
      s[ni] = a;
    }
#pragma unroll
    for (int r = 0; r < 4; ++r) {
      int in_ = irow[r];
      if (in_ >= 0) {
        const unsigned char* ar = adjB + (size_t)in_ * NN;
        float g = grq[r];
#pragma unroll
        for (int ni = 0; ni < 4; ++ni)
          if (jn[ni] >= 0 && ar[jn[ni]]) s[ni][r] += g * gcn[ni];
      }
    }
#pragma unroll
    for (int r = 0; r < 4; ++r) {
      float e0 = __expf(s[0][r]);
      float e1 = __expf(s[1][r]);
      float e2 = __expf(s[2][r]);
      float e3 = __expf(s[3][r]);
      l_r[r] += (e0 + e1) + (e2 + e3);
      int prow = (quad * 4 + r) * 72;
      pw[prow + 0 + l16] = f2bf(e0);
      pw[prow + 16 + l16] = f2bf(e1);
      pw[prow + 32 + l16] = f2bf(e2);
      pw[prow + 48 + l16] = f2bf(e3);
    }
#pragma unroll
    for (int ks = 0; ks < 2; ++ks) {
      bf16x8 pb = *(const bf16x8*)(pw + l16 * 72 + ks * 32 + quad * 8);
      ot[0] = __builtin_amdgcn_mfma_f32_16x16x32_bf16(vaf[0][ks], pb, ot[0], 0, 0, 0);
      ot[1] = __builtin_amdgcn_mfma_f32_16x16x32_bf16(vaf[1][ks], pb, ot[1], 0, 0, 0);
    }
  }
  // partial row-sums + raw partial O (normalization deferred to reduce_k)
#pragma unroll
  for (int r = 0; r < 4; ++r) {
    float ls = l_r[r];
    ls += __shfl_xor(ls, 1);
    ls += __shfl_xor(ls, 2);
    ls += __shfl_xor(ls, 4);
    ls += __shfl_xor(ls, 8);
    if (l16 == 0) aw[quad * 4 + r] = ls;
  }
  float* os = (float*)pw;
#pragma unroll
  for (int mi = 0; mi < 2; ++mi)
#pragma unroll
    for (int r = 0; r < 4; ++r)
      os[l16 * 36 + mi * 16 + quad * 4 + r] = ot[mi][r];
  int bht = bh * 16 + qt;
  size_t pob = (((size_t)bht * 2 + khalf) * 64 + wid * 16) * 32;
  int qr2 = lane >> 2, dg = (lane & 3) * 8;
  *(float4*)&po[pob + qr2 * 32 + dg] = *(float4*)&os[qr2 * 36 + dg];
  *(float4*)&po[pob + qr2 * 32 + dg + 4] = *(float4*)&os[qr2 * 36 + dg + 4];
  if (lane < 16) pl[((size_t)bht * 2 + khalf) * 64 + wid * 16 + lane] = aw[lane];
}

// ---------------- combine K-split halves, normalize, emit hi/lo bf16 ao ----------------
__global__ __launch_bounds__(256) void reduce_k(const float* __restrict__ po,
                                                const float* __restrict__ pl,
                                                short* __restrict__ aoh,
                                                short* __restrict__ aol) {
  int bht = blockIdx.x;                 // 1024
  int bh = bht >> 4, qt = bht & 15;
  int b = bh >> 3, h = bh & 7;
  int t = threadIdx.x;
  int q = t >> 2, dg = (t & 3) * 8;
  size_t b0 = (((size_t)bht * 2 + 0) * 64 + q) * 32 + dg;
  size_t b1 = (((size_t)bht * 2 + 1) * 64 + q) * 32 + dg;
  float4 a0 = *(const float4*)&po[b0];
  float4 a1 = *(const float4*)&po[b0 + 4];
  float4 c0 = *(const float4*)&po[b1];
  float4 c1 = *(const float4*)&po[b1 + 4];
  float l = pl[((size_t)bht * 2) * 64 + q] + pl[((size_t)bht * 2 + 1) * 64 + q];
  float inv = 1.f / l;
  float f[8] = {(a0.x + c0.x) * inv, (a0.y + c0.y) * inv,
                (a0.z + c0.z) * inv, (a0.w + c0.w) * inv,
                (a1.x + c1.x) * inv, (a1.y + c1.y) * inv,
                (a1.z + c1.z) * inv, (a1.w + c1.w) * inv};
  bf16x8 hv, lv;
#pragma unroll
  for (int j = 0; j < 8; ++j) {
    hv[j] = f2bf(f[j]);
    lv[j] = f2bf(f[j] - bf2f(hv[j]));
  }
  size_t ob = (size_t)(b * 1024 + qt * 64 + q) * 256 + h * 32 + dg;
  *(bf16x8*)(aoh + ob) = hv;
  *(bf16x8*)(aol + ob) = lv;
}

// ---------------- proj split-bf16 MFMA GEMM (32-col tiles) + bias + transposed store ----------------
__global__ __launch_bounds__(256, 4) void proj_k(const short* __restrict__ aoh,
                                                 const short* __restrict__ aol,
                                                 const short* __restrict__ wph,
                                                 const short* __restrict__ wpl,
                                                 const float* __restrict__ bias,
                                                 float* __restrict__ out) {
  __shared__ float os_s[4][32 * 20];
  int t = threadIdx.x, wid = t >> 6, lane = t & 63, quad = lane >> 4, l16 = lane & 15;
  int m0 = blockIdx.x * 64, n0 = blockIdx.y * 32;
  int b = m0 >> 10;
  int row = m0 + wid * 16 + l16;
  int p_base = (m0 & 1023) + wid * 16;
  const short* arh = aoh + (size_t)row * 256 + quad * 8;
  const short* arl = aol + (size_t)row * 256 + quad * 8;
  f32x4 acc[2];
  acc[0] = (f32x4){0.f, 0.f, 0.f, 0.f};
  acc[1] = (f32x4){0.f, 0.f, 0.f, 0.f};
#pragma unroll
  for (int kb = 0; kb < 8; ++kb) {
    bf16x8 ah = *(const bf16x8*)(arh + kb * 32);
    bf16x8 al = *(const bf16x8*)(arl + kb * 32);
#pragma unroll
    for (int nt = 0; nt < 2; ++nt) {
      size_t wo = (size_t)(n0 + nt * 16 + l16) * 256 + kb * 32 + quad * 8;
      bf16x8 bh_ = *(const bf16x8*)(wph + wo);
      bf16x8 bl_ = *(const bf16x8*)(wpl + wo);
      acc[nt] = __builtin_amdgcn_mfma_f32_16x16x32_bf16(ah, bh_, acc[nt], 0, 0, 0);
      acc[nt] = __builtin_amdgcn_mfma_f32_16x16x32_bf16(ah, bl_, acc[nt], 0, 0, 0);
      acc[nt] = __builtin_amdgcn_mfma_f32_16x16x32_bf16(al, bh_, acc[nt], 0, 0, 0);
    }
  }
  float* os = &os_s[wid][0];
#pragma unroll
  for (int nt = 0; nt < 2; ++nt) {
    float bv = bias[n0 + nt * 16 + l16];
#pragma unroll
    for (int r = 0; r < 4; ++r)
      os[(nt * 16 + l16) * 20 + quad * 4 + r] = acc[nt][r] + bv;
  }
  int cl = lane >> 1, hf = lane & 1;
  int c = n0 + cl;
  float* orow = out + ((size_t)(b * 256 + c)) * 1024 + p_base;
  *(float4*)(orow + hf * 8) = *(float4*)&os[cl * 20 + hf * 8];
  *(float4*)(orow + hf * 8 + 4) = *(float4*)&os[cl * 20 + hf * 8 + 4];
}

extern "C" void kernel_launch(void* const* d_in, const int* in_sizes, int n_in,
                              void* d_out, int out_size, void* d_ws, size_t ws_size,
                              hipStream_t stream) {
  const float* x      = (const float*)d_in[0];
  const float* w_qkv  = (const float*)d_in[1];
  const float* w_proj = (const float*)d_in[2];
  const float* b_proj = (const float*)d_in[3];
  const float* g0W    = (const float*)d_in[4];
  const float* g0as   = (const float*)d_in[5];
  const float* g0ad   = (const float*)d_in[6];
  const float* g0b    = (const float*)d_in[7];
  const float* g1W    = (const float*)d_in[8];
  const float* g1as   = (const float*)d_in[9];
  const float* g1ad   = (const float*)d_in[10];
  const float* g1b    = (const float*)d_in[11];
  const float* wg2a   = (const float*)d_in[12];
  const float* bg2a   = (const float*)d_in[13];
  float* out = (float*)d_out;
  float* ws = (float*)d_ws;

  size_t o = 0;
  auto alloc = [&](size_t nf) { float* p = ws + o; o += (nf + 15) & ~(size_t)15; return p; };
  float* imp    = alloc(8 * 1024);
  int*   nodeof = (int*)alloc(8 * 1024);
  short* fnG    = (short*)alloc(8 * 112 * 256 / 2);
  short* w0bT   = (short*)alloc(256 * 64 / 2);
  short* w1bT   = (short*)alloc(64 * 64 / 2);
  unsigned char* adj = (unsigned char*)alloc((8 * NN * NN + 3) / 4 + 16);
  float* gwb    = alloc(8 * NN * 8);
  short* xth    = (short*)alloc(1048576);
  short* xtl    = (short*)alloc(1048576);
  short* wqh    = (short*)alloc(98304);
  short* wql    = (short*)alloc(98304);
  short* wph    = (short*)alloc(32768);
  short* wpl    = (short*)alloc(32768);
  short* qh     = (short*)alloc(1048576);
  short* ql     = (short*)alloc(1048576);
  short* kh     = (short*)alloc(1048576);
  short* kl     = (short*)alloc(1048576);
  short* vt     = (short*)alloc(1048576);
  short* aoh    = (short*)alloc(1048576);
  short* aol    = (short*)alloc(1048576);
  float* po     = alloc((size_t)1024 * 2 * 64 * 32);
  float* plv    = alloc((size_t)1024 * 2 * 64);
  if (ws_size < o * sizeof(float)) return;

  importance_k<<<256, 256, 0, stream>>>(x, imp);
  wsplit_k<<<1024, 256, 0, stream>>>(w_qkv, w_proj, wqh, wql, wph, wpl);
  xsplit_k<<<dim3(16, 4, 8), 256, 0, stream>>>(x, xth, xtl);
  prep_k<<<80, 256, 0, stream>>>(g0W, g1W, w0bT, w1bT);
  graph_k<<<8, 1024, 0, stream>>>(x, imp, w0bT, w1bT, g0as, g0ad, g0b,
                                  g1as, g1ad, g1b, wg2a, bg2a,
                                  nodeof, fnG, adj, gwb);
  qkv_k<<<dim3(128, 24), 256, 0, stream>>>(xth, xtl, wqh, wql, qh, ql, kh, kl, vt);
  attn_k<<<dim3(64, 16, 2), 256, 0, stream>>>(qh, ql, kh, kl, vt, nodeof, gwb, adj, po, plv);
  reduce_k<<<1024, 256, 0, stream>>>(po, plv, aoh, aol);
  proj_k<<<dim3(128, 8), 256, 0, stream>>>(aoh, aol, wph, wpl, b_proj, out);
}

// Round 8
// 365.790 us; speedup vs baseline: 1.2703x; 1.0090x over previous
//
#include <hip/hip_runtime.h>
#include <math.h>

#define NB 8
#define CDIM 256
#define HWD 1024
#define NH 8
#define HD 32
#define NN 102
#define GD 64

typedef __attribute__((ext_vector_type(8))) short bf16x8;
typedef __attribute__((ext_vector_type(4))) float f32x4;

__device__ inline short f2bf(float f) {
  union { float f; unsigned u; } v; v.f = f;
  unsigned r = v.u + 0x7fffu + ((v.u >> 16) & 1u);
  return (short)(r >> 16);
}
__device__ inline float bf2f(short s) {
  union { unsigned u; float f; } v;
  v.u = ((unsigned)(unsigned short)s) << 16;
  return v.f;
}

// ---------------- split weights into hi/lo bf16 ([n][k] layout kept) ----------------
__global__ __launch_bounds__(256) void wsplit_k(const float* __restrict__ w_qkv,
                                                const float* __restrict__ w_proj,
                                                short* __restrict__ wqh, short* __restrict__ wql,
                                                short* __restrict__ wph, short* __restrict__ wpl) {
  int t = blockIdx.x * 256 + threadIdx.x;
  if (t < 196608) {
    float v = w_qkv[t];
    short hi = f2bf(v);
    wqh[t] = hi; wql[t] = f2bf(v - bf2f(hi));
  } else {
    int u = t - 196608;
    float v = w_proj[u];
    short hi = f2bf(v);
    wph[u] = hi; wpl[u] = f2bf(v - bf2f(hi));
  }
}

// ---------------- x [b][c][p] -> xt hi/lo bf16 [b][p][c] ----------------
__global__ __launch_bounds__(256) void xsplit_k(const float* __restrict__ x,
                                                short* __restrict__ xth,
                                                short* __restrict__ xtl) {
  __shared__ float tile[64][65];
  int p0 = blockIdx.x * 64, c0 = blockIdx.y * 64, b = blockIdx.z;
  int t = threadIdx.x;
  {
    int g = t >> 6, p = t & 63;
#pragma unroll
    for (int i = 0; i < 16; ++i) {
      int cc = g * 16 + i;
      tile[cc][p] = x[((size_t)(b * 256 + c0 + cc)) * 1024 + p0 + p];
    }
  }
  __syncthreads();
  {
    int p = t >> 2, cs = (t & 3) * 16;
    size_t rb = ((size_t)(b * 1024 + p0 + p)) * 256 + c0 + cs;
#pragma unroll
    for (int g = 0; g < 4; ++g) {
      short4 hv, lv;
      float f0 = tile[cs + g * 4 + 0][p];
      float f1 = tile[cs + g * 4 + 1][p];
      float f2 = tile[cs + g * 4 + 2][p];
      float f3 = tile[cs + g * 4 + 3][p];
      hv.x = f2bf(f0); lv.x = f2bf(f0 - bf2f(hv.x));
      hv.y = f2bf(f1); lv.y = f2bf(f1 - bf2f(hv.y));
      hv.z = f2bf(f2); lv.z = f2bf(f2 - bf2f(hv.z));
      hv.w = f2bf(f3); lv.w = f2bf(f3 - bf2f(hv.w));
      *(short4*)(xth + rb + g * 4) = hv;
      *(short4*)(xtl + rb + g * 4) = lv;
    }
  }
}

// ---------------- prep: bf16-transposed GAT weights ----------------
__global__ __launch_bounds__(256) void prep_k(const float* __restrict__ g0W,
                                              const float* __restrict__ g1W,
                                              short* __restrict__ w0bT,
                                              short* __restrict__ w1bT) {
  int t = blockIdx.x * 256 + threadIdx.x;
  if (t < 16384) {
    int c = t >> 6, f = t & 63;
    w0bT[f * 256 + c] = f2bf(g0W[t]);
  } else if (t < 20480) {
    int u2 = t - 16384;
    int c = u2 >> 6, f = u2 & 63;
    w1bT[f * 64 + c] = f2bf(g1W[u2]);
  }
}

// ---------------- importance = unbiased variance over channels ----------------
__global__ __launch_bounds__(256) void importance_k(const float* __restrict__ x,
                                                    float* __restrict__ imp) {
  __shared__ float red[8][33];
  int bp = blockIdx.x;
  int b = bp >> 5, p0 = (bp & 31) << 5;
  int t = threadIdx.x;
  int pl = t & 31, cg = t >> 5;
  const float* xp = x + (size_t)b * CDIM * HWD + p0 + pl;
  float s = 0.f;
  for (int cc = 0; cc < 32; ++cc) s += xp[(size_t)(cg * 32 + cc) * HWD];
  red[cg][pl] = s;
  __syncthreads();
  float tot = 0.f;
  for (int g = 0; g < 8; ++g) tot += red[g][pl];
  float mean = tot * (1.f / CDIM);
  __syncthreads();
  float v = 0.f;
  for (int cc = 0; cc < 32; ++cc) {
    float d = xp[(size_t)(cg * 32 + cc) * HWD] - mean;
    v += d * d;
  }
  red[cg][pl] = v;
  __syncthreads();
  if (t < 32) {
    float vv = 0.f;
    for (int g = 0; g < 8; ++g) vv += red[g][t];
    imp[b * 1024 + p0 + t] = vv * (1.f / (CDIM - 1));
  }
}

// ---------------- fused graph pipeline: MFMA GAT ----------------
union GraphLDS {
  struct { float sv[1024]; int si[1024]; } tk;
  struct {
    short h0T[64 * 136];
    short alphaB[102 * 136];
    short gB[102 * 72];
  } m;
};

__global__ __launch_bounds__(1024) void graph_k(
    const float* __restrict__ x, const float* __restrict__ imp,
    const short* __restrict__ w0bT, const short* __restrict__ w1bT,
    const float* __restrict__ g0as, const float* __restrict__ g0ad,
    const float* __restrict__ g0b,
    const float* __restrict__ g1as, const float* __restrict__ g1ad,
    const float* __restrict__ g1b,
    const float* __restrict__ wg2a, const float* __restrict__ bg2a,
    int* __restrict__ nodeof, int* __restrict__ topi, short* __restrict__ fnG,
    unsigned char* __restrict__ adjG, float* __restrict__ gwb) {
  __shared__ GraphLDS u;
  __shared__ ushort adjPack[NN][8];
  __shared__ float normL[NN];
  __shared__ float asrcL[NN], adstL[NN];
  __shared__ int topiL[NN];
  int b = blockIdx.x, t = threadIdx.x;
  int wv = t >> 6, lane = t & 63, quad = lane >> 4, l16 = lane & 15;

  // ---- phase T: top-102 bitonic sort ----
  u.tk.sv[t] = imp[b * 1024 + t];
  u.tk.si[t] = t;
  nodeof[b * 1024 + t] = -1;
  __syncthreads();
  for (int k = 2; k <= 1024; k <<= 1) {
    for (int j = k >> 1; j > 0; j >>= 1) {
      int ixj = t ^ j;
      if (ixj > t) {
        bool up = ((t & k) == 0);
        float a = u.tk.sv[t], c = u.tk.sv[ixj];
        if ((a > c) == up) {
          u.tk.sv[t] = c; u.tk.sv[ixj] = a;
          int ti = u.tk.si[t]; u.tk.si[t] = u.tk.si[ixj]; u.tk.si[ixj] = ti;
        }
      }
      __syncthreads();
    }
  }
  if (t >= 1024 - NN) {
    int n = 1023 - t;
    int idx = u.tk.si[t];
    topiL[n] = idx;
    topi[b * 128 + n] = idx;
    nodeof[b * 1024 + idx] = n;
  }
  __syncthreads();

  // ---- phase F: gather -> normalize -> fn bf16 to global; normL ----
  {
    int n = t >> 3, g = t & 7;
    if (n < NN) {
      int idx = topiL[n];
      const float* xb = x + (size_t)b * CDIM * HWD + idx;
      float vbuf[32];
      float ssl = 0.f;
#pragma unroll
      for (int cc = 0; cc < 32; ++cc) {
        float v = xb[(size_t)(g * 32 + cc) * HWD];
        vbuf[cc] = v;
        ssl += v * v;
      }
      ssl += __shfl_xor(ssl, 1);
      ssl += __shfl_xor(ssl, 2);
      ssl += __shfl_xor(ssl, 4);
      float nrm = sqrtf(ssl);
      float rn = 1.f / fmaxf(nrm, 1e-12f);
      if (g == 0) normL[n] = nrm;
      short* fp = fnG + ((size_t)b * 112 + n) * 256 + g * 32;
#pragma unroll
      for (int cc = 0; cc < 32; cc += 4) {
        short4 s4 = {f2bf(vbuf[cc] * rn), f2bf(vbuf[cc + 1] * rn),
                     f2bf(vbuf[cc + 2] * rn), f2bf(vbuf[cc + 3] * rn)};
        *(short4*)(fp + cc) = s4;
      }
    }
  }
  for (int e = t; e < 64 * 34; e += 1024) {
    int f = e / 34, c = 102 + (e % 34);
    u.m.h0T[f * 136 + c] = 0;
  }
  __syncthreads();

  // ---- phase S: cosine sim via MFMA -> adjPack bits + global adj ----
  for (int tile = wv; tile < 49; tile += 16) {
    int I = tile / 7, J = tile % 7;
    const short* ap = fnG + ((size_t)b * 112 + I * 16 + l16) * 256 + quad * 8;
    const short* bp = fnG + ((size_t)b * 112 + J * 16 + l16) * 256 + quad * 8;
    f32x4 acc = (f32x4){0.f, 0.f, 0.f, 0.f};
#pragma unroll
    for (int kb = 0; kb < 8; ++kb)
      acc = __builtin_amdgcn_mfma_f32_16x16x32_bf16(*(const bf16x8*)(ap + kb * 32),
                                                    *(const bf16x8*)(bp + kb * 32), acc, 0, 0, 0);
#pragma unroll
    for (int r = 0; r < 4; ++r) {
      int i = I * 16 + quad * 4 + r, j = J * 16 + l16;
      bool e = (acc[r] > 0.6f) || (i == j);
      unsigned long long m = __ballot(e);
      if (l16 == 0) {
        int row = I * 16 + quad * 4 + r;
        if (row < NN) adjPack[row][J] = (ushort)((m >> (quad * 16)) & 0xFFFFull);
      }
      if (i < NN && j < NN) adjG[(size_t)b * NN * NN + i * NN + j] = e ? 1 : 0;
    }
  }
  __syncthreads();

  // ---- phase G0: h0 = norm * (fn @ W0) -> h0T bf16 ----
  for (int tile = wv; tile < 28; tile += 16) {
    int mt = tile >> 2, nt = tile & 3;
    const short* ap = fnG + ((size_t)b * 112 + mt * 16 + l16) * 256 + quad * 8;
    const short* bp = w0bT + (nt * 16 + l16) * 256 + quad * 8;
    f32x4 acc = (f32x4){0.f, 0.f, 0.f, 0.f};
#pragma unroll
    for (int kb = 0; kb < 8; ++kb)
      acc = __builtin_amdgcn_mfma_f32_16x16x32_bf16(*(const bf16x8*)(ap + kb * 32),
                                                    *(const bf16x8*)(bp + kb * 32), acc, 0, 0, 0);
    int f = nt * 16 + l16;
#pragma unroll
    for (int r = 0; r < 4; ++r) {
      int node = mt * 16 + quad * 4 + r;
      if (node < NN) u.m.h0T[f * 136 + node] = f2bf(acc[r] * normL[node]);
    }
  }
  __syncthreads();

  for (int layer = 0; layer < 2; ++layer) {
    const float* avs = layer ? g1as : g0as;
    const float* avd = layer ? g1ad : g0ad;
    const float* bias = layer ? g1b : g0b;
    {
      int n = t >> 3, g = t & 7;
      if (n < NN) {
        float s1 = 0.f, s2 = 0.f;
#pragma unroll
        for (int uu = 0; uu < 8; ++uu) {
          int f = g * 8 + uu;
          float hv = bf2f(u.m.h0T[f * 136 + n]);
          s1 += hv * avs[f];
          s2 += hv * avd[f];
        }
        s1 += __shfl_xor(s1, 1); s1 += __shfl_xor(s1, 2); s1 += __shfl_xor(s1, 4);
        s2 += __shfl_xor(s2, 1); s2 += __shfl_xor(s2, 2); s2 += __shfl_xor(s2, 4);
        if (g == 0) { asrcL[n] = s1; adstL[n] = s2; }
      }
    }
    __syncthreads();
    for (int i = wv; i < NN; i += 16) {
      float zi = adstL[i];
      int j1 = 64 + lane;
      bool e0 = (adjPack[i][lane >> 4] >> (lane & 15)) & 1;
      bool e1 = (j1 < NN) && ((adjPack[i][j1 >> 4] >> (j1 & 15)) & 1);
      float p0 = 0.f, p1 = 0.f;
      if (e0) { float z = zi + asrcL[lane]; p0 = __expf(z > 0.f ? z : 0.2f * z); }
      if (e1) { float z = zi + asrcL[j1]; p1 = __expf(z > 0.f ? z : 0.2f * z); }
      float s = p0 + p1;
      s += __shfl_xor(s, 1); s += __shfl_xor(s, 2); s += __shfl_xor(s, 4);
      s += __shfl_xor(s, 8); s += __shfl_xor(s, 16); s += __shfl_xor(s, 32);
      float inv = 1.f / s;
      u.m.alphaB[i * 136 + lane] = f2bf(p0 * inv);
      u.m.alphaB[i * 136 + 64 + lane] = f2bf(p1 * inv);
    }
    __syncthreads();
    for (int tile = wv; tile < 28; tile += 16) {
      int mt = tile >> 2, nt = tile & 3;
      int ar = mt * 16 + l16; if (ar > NN - 1) ar = NN - 1;
      const short* ap = &u.m.alphaB[ar * 136 + quad * 8];
      const short* bp = &u.m.h0T[(nt * 16 + l16) * 136 + quad * 8];
      f32x4 acc = (f32x4){0.f, 0.f, 0.f, 0.f};
#pragma unroll
      for (int kb = 0; kb < 4; ++kb)
        acc = __builtin_amdgcn_mfma_f32_16x16x32_bf16(*(const bf16x8*)(ap + kb * 32),
                                                      *(const bf16x8*)(bp + kb * 32), acc, 0, 0, 0);
      int f = nt * 16 + l16;
      float bv = bias[f];
#pragma unroll
      for (int r = 0; r < 4; ++r) {
        int i = mt * 16 + quad * 4 + r;
        if (i < NN) u.m.gB[i * 72 + f] = f2bf(fmaxf(acc[r] + bv, 0.f));
      }
    }
    __syncthreads();
    if (layer == 0) {
      for (int tile = wv; tile < 28; tile += 16) {
        int mt = tile >> 2, nt = tile & 3;
        int ar = mt * 16 + l16; if (ar > NN - 1) ar = NN - 1;
        const short* ap = &u.m.gB[ar * 72 + quad * 8];
        const short* bp = w1bT + (nt * 16 + l16) * 64 + quad * 8;
        f32x4 acc = (f32x4){0.f, 0.f, 0.f, 0.f};
#pragma unroll
        for (int kb = 0; kb < 2; ++kb)
          acc = __builtin_amdgcn_mfma_f32_16x16x32_bf16(*(const bf16x8*)(ap + kb * 32),
                                                        *(const bf16x8*)(bp + kb * 32), acc, 0, 0, 0);
        int f = nt * 16 + l16;
#pragma unroll
        for (int r = 0; r < 4; ++r) {
          int node = mt * 16 + quad * 4 + r;
          if (node < NN) u.m.h0T[f * 136 + node] = f2bf(acc[r]);
        }
      }
      __syncthreads();
    }
  }
  float* wgL = (float*)&u.m.alphaB[0];
  if (t < 512) wgL[t] = wg2a[t];
  __syncthreads();
  if (t < NN * NH) {
    int n = t >> 3, h = t & 7;
    float z = bg2a[h];
#pragma unroll
    for (int c = 0; c < GD; ++c) z += bf2f(u.m.gB[n * 72 + c]) * wgL[h * 64 + c];
    gwb[((size_t)b * NN + n) * NH + h] = 1.f / (1.f + __expf(-z));
  }
}

// ---------------- position-space graph structures: 1024-bit adj rows + per-position gates ----------------
__global__ __launch_bounds__(128) void posadj_k(const int* __restrict__ nodeof,
                                                const int* __restrict__ topi,
                                                const unsigned char* __restrict__ adjG,
                                                const float* __restrict__ gwb,
                                                unsigned long long* __restrict__ posadj,
                                                float* __restrict__ gwp) {
  int b = blockIdx.y, p = blockIdx.x * 128 + threadIdx.x;
  int n = nodeof[b * 1024 + p];
#pragma unroll
  for (int h = 0; h < 8; ++h)
    gwp[(size_t)(b * 8 + h) * 1024 + p] =
        (n >= 0) ? gwb[((size_t)b * NN + n) * NH + h] : 0.f;
  unsigned long long m[16];
#pragma unroll
  for (int w = 0; w < 16; ++w) m[w] = 0;
  if (n >= 0) {
    const unsigned char* ar = adjG + (size_t)b * NN * NN + (size_t)n * NN;
    for (int nj = 0; nj < NN; ++nj) {
      if (ar[nj]) {
        int pj = topi[b * 128 + nj];
        m[pj >> 6] |= 1ull << (pj & 63);
      }
    }
  }
  unsigned long long* dst = posadj + (size_t)(b * 1024 + p) * 16;
#pragma unroll
  for (int w = 0; w < 16; ++w) dst[w] = m[w];
}

// ---------------- QKV split-bf16 MFMA GEMM (32-col tiles) ----------------
__global__ __launch_bounds__(256, 4) void qkv_k(const short* __restrict__ xth,
                                                const short* __restrict__ xtl,
                                                const short* __restrict__ wqh,
                                                const short* __restrict__ wql,
                                                short* __restrict__ qhp, short* __restrict__ qlp,
                                                short* __restrict__ khp, short* __restrict__ klp,
                                                short* __restrict__ vtp) {
  __shared__ short vs_s[4][32 * 24];
  int t = threadIdx.x, wid = t >> 6, lane = t & 63, quad = lane >> 4, l16 = lane & 15;
  int m0 = blockIdx.x * 64, y = blockIdx.y;
  int b = m0 >> 10;
  int row = m0 + wid * 16 + l16;
  int p_base = (m0 & 1023) + wid * 16;
  int qi = y >> 3, n0 = (y & 7) * 32;
  const short* wh = wqh + ((size_t)qi * 256 + n0) * 256;
  const short* wl = wql + ((size_t)qi * 256 + n0) * 256;
  const short* arh = xth + (size_t)row * 256 + quad * 8;
  const short* arl = xtl + (size_t)row * 256 + quad * 8;
  f32x4 acc[2];
  acc[0] = (f32x4){0.f, 0.f, 0.f, 0.f};
  acc[1] = (f32x4){0.f, 0.f, 0.f, 0.f};
#pragma unroll
  for (int kb = 0; kb < 8; ++kb) {
    bf16x8 ah = *(const bf16x8*)(arh + kb * 32);
    bf16x8 al = *(const bf16x8*)(arl + kb * 32);
#pragma unroll
    for (int nt = 0; nt < 2; ++nt) {
      size_t wo = (size_t)(nt * 16 + l16) * 256 + kb * 32 + quad * 8;
      bf16x8 bh_ = *(const bf16x8*)(wh + wo);
      bf16x8 bl_ = *(const bf16x8*)(wl + wo);
      acc[nt] = __builtin_amdgcn_mfma_f32_16x16x32_bf16(ah, bh_, acc[nt], 0, 0, 0);
      acc[nt] = __builtin_amdgcn_mfma_f32_16x16x32_bf16(ah, bl_, acc[nt], 0, 0, 0);
      acc[nt] = __builtin_amdgcn_mfma_f32_16x16x32_bf16(al, bh_, acc[nt], 0, 0, 0);
    }
  }
  if (qi < 2) {
    const float scale = (qi == 0) ? 0.17677669529663687f : 1.f;
    short* hp = (qi == 0) ? qhp : khp;
    short* lp = (qi == 0) ? qlp : klp;
#pragma unroll
    for (int nt = 0; nt < 2; ++nt) {
      int nq = n0 + nt * 16 + l16;
      int h = nq >> 5, d = nq & 31;
#pragma unroll
      for (int r = 0; r < 4; ++r) {
        int p = p_base + quad * 4 + r;
        float v = acc[nt][r] * scale;
        short hi = f2bf(v);
        short lo = f2bf(v - bf2f(hi));
        size_t e = ((size_t)(b * 8 + h) * 1024 + p) * 32 + d;
        hp[e] = hi;
        lp[e] = lo;
      }
    }
  } else {
    short* vs = &vs_s[wid][0];
#pragma unroll
    for (int nt = 0; nt < 2; ++nt)
#pragma unroll
      for (int r = 0; r < 4; ++r)
        vs[(nt * 16 + l16) * 24 + quad * 4 + r] = f2bf(acc[nt][r]);
    int cl = lane >> 1, hf = lane & 1;
    int nq = n0 + cl;
    int h = nq >> 5, d = nq & 31;
    size_t rb = ((size_t)(b * 8 + h) * 32 + d) * 1024 + p_base + hf * 8;
    *(bf16x8*)(vtp + rb) = *(const bf16x8*)(vs + cl * 24 + hf * 8);
  }
}

// ---------------- flash attention: bitmask graph-mod, K-split 2x, deferred-sum ----------------
__global__ __launch_bounds__(256, 4) void attn_k(const short* __restrict__ qh,
                                                 const short* __restrict__ ql,
                                                 const short* __restrict__ kh,
                                                 const short* __restrict__ kl,
                                                 const short* __restrict__ vt,
                                                 const float* __restrict__ gwp,
                                                 const unsigned long long* __restrict__ posadj,
                                                 float* __restrict__ po,
                                                 float* __restrict__ pl) {
  __shared__ __align__(16) short p_s[4][16 * 72];
  __shared__ float aw_s[4][16];
  int t = threadIdx.x;
  int wid = t >> 6, lane = t & 63, quad = lane >> 4, l16 = lane & 15;
  int bh = blockIdx.x, b = bh >> 3;   // bh fastest -> co-XCD q-tiles
  int qt = blockIdx.y, khalf = blockIdx.z;
  int q0 = qt * 64 + wid * 16;
  size_t base = (size_t)bh * 32768;
  short* pw = &p_s[wid][0];
  float* aw = &aw_s[wid][0];

  size_t qoff = base + (size_t)(q0 + l16) * 32 + quad * 8;
  bf16x8 qhf = *(const bf16x8*)(qh + qoff);
  bf16x8 qlf = *(const bf16x8*)(ql + qoff);

  const float* gwpBH = gwp + (size_t)bh * 1024;
  const unsigned long long* paB = posadj + (size_t)b * 1024 * 16;
  float grq[4];
#pragma unroll
  for (int r = 0; r < 4; ++r) grq[r] = gwpBH[q0 + quad * 4 + r];

  f32x4 ot[2];
  ot[0] = (f32x4){0.f, 0.f, 0.f, 0.f};
  ot[1] = (f32x4){0.f, 0.f, 0.f, 0.f};
  float l_r[4] = {0.f, 0.f, 0.f, 0.f};

  for (int ch = khalf * 8; ch < khalf * 8 + 8; ++ch) {
    int c0 = ch * 64;
    bf16x8 khf[4], klf[4];
#pragma unroll
    for (int ni = 0; ni < 4; ++ni) {
      size_t off = base + (size_t)(c0 + ni * 16 + l16) * 32 + quad * 8;
      khf[ni] = *(const bf16x8*)(kh + off);
      klf[ni] = *(const bf16x8*)(kl + off);
    }
    bf16x8 vaf[2][2];
#pragma unroll
    for (int mi = 0; mi < 2; ++mi)
#pragma unroll
      for (int ks = 0; ks < 2; ++ks)
        vaf[mi][ks] = *(const bf16x8*)(vt + base + (size_t)(mi * 16 + l16) * 1024 +
                                       c0 + ks * 32 + quad * 8);
    // graph-mod inputs: coalesced gates + one u64 adjacency word per q-row
    float gc[4];
#pragma unroll
    for (int ni = 0; ni < 4; ++ni) gc[ni] = gwpBH[c0 + ni * 16 + l16];
    unsigned long long mr[4];
#pragma unroll
    for (int r = 0; r < 4; ++r)
      mr[r] = paB[(size_t)(q0 + quad * 4 + r) * 16 + ch];
    f32x4 s[4];
#pragma unroll
    for (int ni = 0; ni < 4; ++ni) {
      f32x4 a = (f32x4){0.f, 0.f, 0.f, 0.f};
      a = __builtin_amdgcn_mfma_f32_16x16x32_bf16(qhf, khf[ni], a, 0, 0, 0);
      a = __builtin_amdgcn_mfma_f32_16x16x32_bf16(qhf, klf[ni], a, 0, 0, 0);
      a = __builtin_amdgcn_mfma_f32_16x16x32_bf16(qlf, khf[ni], a, 0, 0, 0);
      s[ni] = a;
    }
#pragma unroll
    for (int r = 0; r < 4; ++r) {
#pragma unroll
      for (int ni = 0; ni < 4; ++ni) {
        bool bit = (mr[r] >> (ni * 16 + l16)) & 1ull;
        s[ni][r] += bit ? grq[r] * gc[ni] : 0.f;
      }
    }
#pragma unroll
    for (int r = 0; r < 4; ++r) {
      float e0 = __expf(s[0][r]);
      float e1 = __expf(s[1][r]);
      float e2 = __expf(s[2][r]);
      float e3 = __expf(s[3][r]);
      l_r[r] += (e0 + e1) + (e2 + e3);
      int prow = (quad * 4 + r) * 72;
      pw[prow + 0 + l16] = f2bf(e0);
      pw[prow + 16 + l16] = f2bf(e1);
      pw[prow + 32 + l16] = f2bf(e2);
      pw[prow + 48 + l16] = f2bf(e3);
    }
#pragma unroll
    for (int ks = 0; ks < 2; ++ks) {
      bf16x8 pb = *(const bf16x8*)(pw + l16 * 72 + ks * 32 + quad * 8);
      ot[0] = __builtin_amdgcn_mfma_f32_16x16x32_bf16(vaf[0][ks], pb, ot[0], 0, 0, 0);
      ot[1] = __builtin_amdgcn_mfma_f32_16x16x32_bf16(vaf[1][ks], pb, ot[1], 0, 0, 0);
    }
  }
  // partial row-sums + raw partial O (normalization deferred to reduce_k)
#pragma unroll
  for (int r = 0; r < 4; ++r) {
    float ls = l_r[r];
    ls += __shfl_xor(ls, 1);
    ls += __shfl_xor(ls, 2);
    ls += __shfl_xor(ls, 4);
    ls += __shfl_xor(ls, 8);
    if (l16 == 0) aw[quad * 4 + r] = ls;
  }
  float* os = (float*)pw;
#pragma unroll
  for (int mi = 0; mi < 2; ++mi)
#pragma unroll
    for (int r = 0; r < 4; ++r)
      os[l16 * 36 + mi * 16 + quad * 4 + r] = ot[mi][r];
  int bht = bh * 16 + qt;
  size_t pob = (((size_t)bht * 2 + khalf) * 64 + wid * 16) * 32;
  int qr2 = lane >> 2, dg = (lane & 3) * 8;
  *(float4*)&po[pob + qr2 * 32 + dg] = *(float4*)&os[qr2 * 36 + dg];
  *(float4*)&po[pob + qr2 * 32 + dg + 4] = *(float4*)&os[qr2 * 36 + dg + 4];
  if (lane < 16) pl[((size_t)bht * 2 + khalf) * 64 + wid * 16 + lane] = aw[lane];
}

// ---------------- combine K-split halves, normalize, emit hi/lo bf16 ao ----------------
__global__ __launch_bounds__(256) void reduce_k(const float* __restrict__ po,
                                                const float* __restrict__ pl,
                                                short* __restrict__ aoh,
                                                short* __restrict__ aol) {
  int bht = blockIdx.x;
  int bh = bht >> 4, qt = bht & 15;
  int b = bh >> 3, h = bh & 7;
  int t = threadIdx.x;
  int q = t >> 2, dg = (t & 3) * 8;
  size_t b0 = (((size_t)bht * 2 + 0) * 64 + q) * 32 + dg;
  size_t b1 = (((size_t)bht * 2 + 1) * 64 + q) * 32 + dg;
  float4 a0 = *(const float4*)&po[b0];
  float4 a1 = *(const float4*)&po[b0 + 4];
  float4 c0 = *(const float4*)&po[b1];
  float4 c1 = *(const float4*)&po[b1 + 4];
  float l = pl[((size_t)bht * 2) * 64 + q] + pl[((size_t)bht * 2 + 1) * 64 + q];
  float inv = 1.f / l;
  float f[8] = {(a0.x + c0.x) * inv, (a0.y + c0.y) * inv,
                (a0.z + c0.z) * inv, (a0.w + c0.w) * inv,
                (a1.x + c1.x) * inv, (a1.y + c1.y) * inv,
                (a1.z + c1.z) * inv, (a1.w + c1.w) * inv};
  bf16x8 hv, lv;
#pragma unroll
  for (int j = 0; j < 8; ++j) {
    hv[j] = f2bf(f[j]);
    lv[j] = f2bf(f[j] - bf2f(hv[j]));
  }
  size_t ob = (size_t)(b * 1024 + qt * 64 + q) * 256 + h * 32 + dg;
  *(bf16x8*)(aoh + ob) = hv;
  *(bf16x8*)(aol + ob) = lv;
}

// ---------------- proj split-bf16 MFMA GEMM (32-col tiles) + bias + transposed store ----------------
__global__ __launch_bounds__(256, 4) void proj_k(const short* __restrict__ aoh,
                                                 const short* __restrict__ aol,
                                                 const short* __restrict__ wph,
                                                 const short* __restrict__ wpl,
                                                 const float* __restrict__ bias,
                                                 float* __restrict__ out) {
  __shared__ float os_s[4][32 * 20];
  int t = threadIdx.x, wid = t >> 6, lane = t & 63, quad = lane >> 4, l16 = lane & 15;
  int m0 = blockIdx.x * 64, n0 = blockIdx.y * 32;
  int b = m0 >> 10;
  int row = m0 + wid * 16 + l16;
  int p_base = (m0 & 1023) + wid * 16;
  const short* arh = aoh + (size_t)row * 256 + quad * 8;
  const short* arl = aol + (size_t)row * 256 + quad * 8;
  f32x4 acc[2];
  acc[0] = (f32x4){0.f, 0.f, 0.f, 0.f};
  acc[1] = (f32x4){0.f, 0.f, 0.f, 0.f};
#pragma unroll
  for (int kb = 0; kb < 8; ++kb) {
    bf16x8 ah = *(const bf16x8*)(arh + kb * 32);
    bf16x8 al = *(const bf16x8*)(arl + kb * 32);
#pragma unroll
    for (int nt = 0; nt < 2; ++nt) {
      size_t wo = (size_t)(n0 + nt * 16 + l16) * 256 + kb * 32 + quad * 8;
      bf16x8 bh_ = *(const bf16x8*)(wph + wo);
      bf16x8 bl_ = *(const bf16x8*)(wpl + wo);
      acc[nt] = __builtin_amdgcn_mfma_f32_16x16x32_bf16(ah, bh_, acc[nt], 0, 0, 0);
      acc[nt] = __builtin_amdgcn_mfma_f32_16x16x32_bf16(ah, bl_, acc[nt], 0, 0, 0);
      acc[nt] = __builtin_amdgcn_mfma_f32_16x16x32_bf16(al, bh_, acc[nt], 0, 0, 0);
    }
  }
  float* os = &os_s[wid][0];
#pragma unroll
  for (int nt = 0; nt < 2; ++nt) {
    float bv = bias[n0 + nt * 16 + l16];
#pragma unroll
    for (int r = 0; r < 4; ++r)
      os[(nt * 16 + l16) * 20 + quad * 4 + r] = acc[nt][r] + bv;
  }
  int cl = lane >> 1, hf = lane & 1;
  int c = n0 + cl;
  float* orow = out + ((size_t)(b * 256 + c)) * 1024 + p_base;
  *(float4*)(orow + hf * 8) = *(float4*)&os[cl * 20 + hf * 8];
  *(float4*)(orow + hf * 8 + 4) = *(float4*)&os[cl * 20 + hf * 8 + 4];
}

extern "C" void kernel_launch(void* const* d_in, const int* in_sizes, int n_in,
                              void* d_out, int out_size, void* d_ws, size_t ws_size,
                              hipStream_t stream) {
  const float* x      = (const float*)d_in[0];
  const float* w_qkv  = (const float*)d_in[1];
  const float* w_proj = (const float*)d_in[2];
  const float* b_proj = (const float*)d_in[3];
  const float* g0W    = (const float*)d_in[4];
  const float* g0as   = (const float*)d_in[5];
  const float* g0ad   = (const float*)d_in[6];
  const float* g0b    = (const float*)d_in[7];
  const float* g1W    = (const float*)d_in[8];
  const float* g1as   = (const float*)d_in[9];
  const float* g1ad   = (const float*)d_in[10];
  const float* g1b    = (const float*)d_in[11];
  const float* wg2a   = (const float*)d_in[12];
  const float* bg2a   = (const float*)d_in[13];
  float* out = (float*)d_out;
  float* ws = (float*)d_ws;

  size_t o = 0;
  auto alloc = [&](size_t nf) { float* p = ws + o; o += (nf + 15) & ~(size_t)15; return p; };
  float* imp    = alloc(8 * 1024);
  int*   nodeof = (int*)alloc(8 * 1024);
  int*   topi   = (int*)alloc(8 * 128);
  short* fnG    = (short*)alloc(8 * 112 * 256 / 2);
  short* w0bT   = (short*)alloc(256 * 64 / 2);
  short* w1bT   = (short*)alloc(64 * 64 / 2);
  unsigned char* adj = (unsigned char*)alloc((8 * NN * NN + 3) / 4 + 16);
  float* gwb    = alloc(8 * NN * 8);
  unsigned long long* posadj = (unsigned long long*)alloc(8 * 1024 * 16 * 2);
  float* gwp    = alloc(64 * 1024);
  short* xth    = (short*)alloc(1048576);
  short* xtl    = (short*)alloc(1048576);
  short* wqh    = (short*)alloc(98304);
  short* wql    = (short*)alloc(98304);
  short* wph    = (short*)alloc(32768);
  short* wpl    = (short*)alloc(32768);
  short* qh     = (short*)alloc(1048576);
  short* ql     = (short*)alloc(1048576);
  short* kh     = (short*)alloc(1048576);
  short* kl     = (short*)alloc(1048576);
  short* vt     = (short*)alloc(1048576);
  short* aoh    = (short*)alloc(1048576);
  short* aol    = (short*)alloc(1048576);
  float* po     = alloc((size_t)1024 * 2 * 64 * 32);
  float* plv    = alloc((size_t)1024 * 2 * 64);
  if (ws_size < o * sizeof(float)) return;

  importance_k<<<256, 256, 0, stream>>>(x, imp);
  wsplit_k<<<1024, 256, 0, stream>>>(w_qkv, w_proj, wqh, wql, wph, wpl);
  xsplit_k<<<dim3(16, 4, 8), 256, 0, stream>>>(x, xth, xtl);
  prep_k<<<80, 256, 0, stream>>>(g0W, g1W, w0bT, w1bT);
  graph_k<<<8, 1024, 0, stream>>>(x, imp, w0bT, w1bT, g0as, g0ad, g0b,
                                  g1as, g1ad, g1b, wg2a, bg2a,
                                  nodeof, topi, fnG, adj, gwb);
  posadj_k<<<dim3(8, 8), 128, 0, stream>>>(nodeof, topi, adj, gwb, posadj, gwp);
  qkv_k<<<dim3(128, 24), 256, 0, stream>>>(xth, xtl, wqh, wql, qh, ql, kh, kl, vt);
  attn_k<<<dim3(64, 16, 2), 256, 0, stream>>>(qh, ql, kh, kl, vt, gwp, posadj, po, plv);
  reduce_k<<<1024, 256, 0, stream>>>(po, plv, aoh, aol);
  proj_k<<<dim3(128, 8), 256, 0, stream>>>(aoh, aol, wph, wpl, b_proj, out);
}

// Round 9
// 300.914 us; speedup vs baseline: 1.5442x; 1.2156x over previous
//
#include <hip/hip_runtime.h>
#include <math.h>

#define NB 8
#define CDIM 256
#define HWD 1024
#define NH 8
#define HD 32
#define NN 102
#define GD 64

typedef __attribute__((ext_vector_type(8))) short bf16x8;
typedef __attribute__((ext_vector_type(4))) float f32x4;

__device__ inline short f2bf(float f) {
  union { float f; unsigned u; } v; v.f = f;
  unsigned r = v.u + 0x7fffu + ((v.u >> 16) & 1u);
  return (short)(r >> 16);
}
__device__ inline float bf2f(short s) {
  union { unsigned u; float f; } v;
  v.u = ((unsigned)(unsigned short)s) << 16;
  return v.f;
}

// ---------------- merged: split big weights hi/lo + bf16-transposed GAT weights ----------------
__global__ __launch_bounds__(256) void wsplitprep_k(const float* __restrict__ w_qkv,
                                                    const float* __restrict__ w_proj,
                                                    const float* __restrict__ g0W,
                                                    const float* __restrict__ g1W,
                                                    short* __restrict__ wqh, short* __restrict__ wql,
                                                    short* __restrict__ wph, short* __restrict__ wpl,
                                                    short* __restrict__ w0bT,
                                                    short* __restrict__ w1bT) {
  int bx = blockIdx.x;
  if (bx < 1024) {
    int t = bx * 256 + threadIdx.x;
    if (t < 196608) {
      float v = w_qkv[t];
      short hi = f2bf(v);
      wqh[t] = hi; wql[t] = f2bf(v - bf2f(hi));
    } else {
      int u = t - 196608;
      float v = w_proj[u];
      short hi = f2bf(v);
      wph[u] = hi; wpl[u] = f2bf(v - bf2f(hi));
    }
  } else {
    int t = (bx - 1024) * 256 + threadIdx.x;
    if (t < 16384) {
      int c = t >> 6, f = t & 63;
      w0bT[f * 256 + c] = f2bf(g0W[t]);
    } else if (t < 20480) {
      int u2 = t - 16384;
      int c = u2 >> 6, f = u2 & 63;
      w1bT[f * 64 + c] = f2bf(g1W[u2]);
    }
  }
}

// ---------------- x [b][c][p] -> xt hi/lo bf16 [b][p][c] ----------------
__global__ __launch_bounds__(256) void xsplit_k(const float* __restrict__ x,
                                                short* __restrict__ xth,
                                                short* __restrict__ xtl) {
  __shared__ float tile[64][65];
  int p0 = blockIdx.x * 64, c0 = blockIdx.y * 64, b = blockIdx.z;
  int t = threadIdx.x;
  {
    int g = t >> 6, p = t & 63;
#pragma unroll
    for (int i = 0; i < 16; ++i) {
      int cc = g * 16 + i;
      tile[cc][p] = x[((size_t)(b * 256 + c0 + cc)) * 1024 + p0 + p];
    }
  }
  __syncthreads();
  {
    int p = t >> 2, cs = (t & 3) * 16;
    size_t rb = ((size_t)(b * 1024 + p0 + p)) * 256 + c0 + cs;
#pragma unroll
    for (int g = 0; g < 4; ++g) {
      short4 hv, lv;
      float f0 = tile[cs + g * 4 + 0][p];
      float f1 = tile[cs + g * 4 + 1][p];
      float f2 = tile[cs + g * 4 + 2][p];
      float f3 = tile[cs + g * 4 + 3][p];
      hv.x = f2bf(f0); lv.x = f2bf(f0 - bf2f(hv.x));
      hv.y = f2bf(f1); lv.y = f2bf(f1 - bf2f(hv.y));
      hv.z = f2bf(f2); lv.z = f2bf(f2 - bf2f(hv.z));
      hv.w = f2bf(f3); lv.w = f2bf(f3 - bf2f(hv.w));
      *(short4*)(xth + rb + g * 4) = hv;
      *(short4*)(xtl + rb + g * 4) = lv;
    }
  }
}

// ---------------- importance = unbiased variance over channels ----------------
__global__ __launch_bounds__(256) void importance_k(const float* __restrict__ x,
                                                    float* __restrict__ imp) {
  __shared__ float red[8][33];
  int bp = blockIdx.x;
  int b = bp >> 5, p0 = (bp & 31) << 5;
  int t = threadIdx.x;
  int pl = t & 31, cg = t >> 5;
  const float* xp = x + (size_t)b * CDIM * HWD + p0 + pl;
  float s = 0.f;
  for (int cc = 0; cc < 32; ++cc) s += xp[(size_t)(cg * 32 + cc) * HWD];
  red[cg][pl] = s;
  __syncthreads();
  float tot = 0.f;
  for (int g = 0; g < 8; ++g) tot += red[g][pl];
  float mean = tot * (1.f / CDIM);
  __syncthreads();
  float v = 0.f;
  for (int cc = 0; cc < 32; ++cc) {
    float d = xp[(size_t)(cg * 32 + cc) * HWD] - mean;
    v += d * d;
  }
  red[cg][pl] = v;
  __syncthreads();
  if (t < 32) {
    float vv = 0.f;
    for (int g = 0; g < 8; ++g) vv += red[g][t];
    imp[b * 1024 + p0 + t] = vv * (1.f / (CDIM - 1));
  }
}

// ---------------- fused graph pipeline v3: all-LDS feats, fused coeffs, posadj tail ----------------
union GraphLDS {
  struct { float sv[1024]; int si[1024]; } tk;          // 8 KB (sort)
  short featsB[NN * 264];                                // 53.9 KB (bf16 raw feats)
  struct { short alphaB[NN * 136]; short gB[NN * 72]; } ly;  // 42.4 KB
};

__global__ __launch_bounds__(1024) void graph_k(
    const float* __restrict__ imp,
    const short* __restrict__ xth, const short* __restrict__ xtl,
    const short* __restrict__ w0bT, const short* __restrict__ w1bT,
    const float* __restrict__ g0as, const float* __restrict__ g0ad,
    const float* __restrict__ g0b,
    const float* __restrict__ g1as, const float* __restrict__ g1ad,
    const float* __restrict__ g1b,
    const float* __restrict__ wg2a, const float* __restrict__ bg2a,
    short* __restrict__ h0tG,                 // [b][64][128] bf16 scratch
    float* __restrict__ gwp,                  // [b*8+h][1024]
    unsigned long long* __restrict__ posadj)  // [b*16+w][1024]
{
  __shared__ GraphLDS u;
  __shared__ ushort adjPack[NN][8];
  __shared__ float rnL[NN];
  __shared__ float asrcL[112], adstL[112];
  __shared__ int topiL[NN];
  __shared__ int nodeofL[1024];
  int b = blockIdx.x, t = threadIdx.x;
  int wv = t >> 6, lane = t & 63, quad = lane >> 4, l16 = lane & 15;
  short* hb = h0tG + (size_t)b * 64 * 128;

  // ---- phase T: top-102 bitonic sort (LDS-only) ----
  u.tk.sv[t] = imp[b * 1024 + t];
  u.tk.si[t] = t;
  nodeofL[t] = -1;
  // zero h0tG pad columns [102,128) while sorting
  for (int e = t; e < 64 * 26; e += 1024) hb[(e / 26) * 128 + 102 + (e % 26)] = 0;
  __syncthreads();
  for (int k = 2; k <= 1024; k <<= 1) {
    for (int j = k >> 1; j > 0; j >>= 1) {
      int ixj = t ^ j;
      if (ixj > t) {
        bool up = ((t & k) == 0);
        float a = u.tk.sv[t], c = u.tk.sv[ixj];
        if ((a > c) == up) {
          u.tk.sv[t] = c; u.tk.sv[ixj] = a;
          int ti = u.tk.si[t]; u.tk.si[t] = u.tk.si[ixj]; u.tk.si[ixj] = ti;
        }
      }
      __syncthreads();
    }
  }
  if (t >= 1024 - NN) {
    int n = 1023 - t;
    int idx = u.tk.si[t];
    topiL[n] = idx;
    nodeofL[idx] = n;
  }
  __syncthreads();

  // ---- phase F: coalesced gather from xth/xtl -> featsB LDS (bf16 = hi verbatim) + 1/norm ----
  {
    int n = t >> 3, g = t & 7;
    if (n < NN) {
      int p = topiL[n];
      const short* xh = xth + ((size_t)(b * 1024 + p)) * 256 + g * 32;
      const short* xl = xtl + ((size_t)(b * 1024 + p)) * 256 + g * 32;
      float ss = 0.f;
#pragma unroll
      for (int c8 = 0; c8 < 4; ++c8) {
        bf16x8 hv = *(const bf16x8*)(xh + c8 * 8);
        bf16x8 lv = *(const bf16x8*)(xl + c8 * 8);
#pragma unroll
        for (int j = 0; j < 8; ++j) {
          float f = bf2f(hv[j]) + bf2f(lv[j]);
          ss += f * f;
        }
        *(bf16x8*)(&u.featsB[n * 264 + g * 32 + c8 * 8]) = hv;
      }
      ss += __shfl_xor(ss, 1);
      ss += __shfl_xor(ss, 2);
      ss += __shfl_xor(ss, 4);
      if (g == 0) rnL[n] = 1.f / fmaxf(sqrtf(ss), 1e-12f);
    }
  }
  __syncthreads();

  // ---- phase S: sim = (feats.featsT)*rn_i*rn_j via MFMA (all-LDS) -> adjPack ----
  for (int tile = wv; tile < 49; tile += 16) {
    int I = tile / 7, J = tile % 7;
    int rA = I * 16 + l16; if (rA > NN - 1) rA = NN - 1;
    int rB = J * 16 + l16; if (rB > NN - 1) rB = NN - 1;
    const short* ap = &u.featsB[rA * 264 + quad * 8];
    const short* bp = &u.featsB[rB * 264 + quad * 8];
    f32x4 acc = (f32x4){0.f, 0.f, 0.f, 0.f};
#pragma unroll
    for (int kb = 0; kb < 8; ++kb)
      acc = __builtin_amdgcn_mfma_f32_16x16x32_bf16(*(const bf16x8*)(ap + kb * 32),
                                                    *(const bf16x8*)(bp + kb * 32), acc, 0, 0, 0);
#pragma unroll
    for (int r = 0; r < 4; ++r) {
      int i = I * 16 + quad * 4 + r, j = J * 16 + l16;
      bool e = (i < NN && j < NN) &&
               ((acc[r] * rnL[i < NN ? i : 0] * rnL[j < NN ? j : 0] > 0.6f) || (i == j));
      unsigned long long m = __ballot(e);
      if (l16 == 0 && i < NN) adjPack[i][J] = (ushort)((m >> (quad * 16)) & 0xFFFFull);
    }
  }
  __syncthreads();

  // ---- phase G0: h0 = feats @ W0 -> h0tG global bf16 [f][node]; asrc/adst fused ----
  if (wv < 7) {
    int mt = wv;
    int ar = mt * 16 + l16; if (ar > NN - 1) ar = NN - 1;
    const short* ap = &u.featsB[ar * 264 + quad * 8];
    float s1[4] = {0.f, 0.f, 0.f, 0.f}, s2[4] = {0.f, 0.f, 0.f, 0.f};
#pragma unroll
    for (int nt = 0; nt < 4; ++nt) {
      const short* bp = w0bT + (nt * 16 + l16) * 256 + quad * 8;
      f32x4 acc = (f32x4){0.f, 0.f, 0.f, 0.f};
#pragma unroll
      for (int kb = 0; kb < 8; ++kb)
        acc = __builtin_amdgcn_mfma_f32_16x16x32_bf16(*(const bf16x8*)(ap + kb * 32),
                                                      *(const bf16x8*)(bp + kb * 32), acc, 0, 0, 0);
      int f = nt * 16 + l16;
      float a_s = g0as[f], a_d = g0ad[f];
#pragma unroll
      for (int r = 0; r < 4; ++r) {
        int node = mt * 16 + quad * 4 + r;
        if (node < NN) hb[f * 128 + node] = f2bf(acc[r]);
        s1[r] += acc[r] * a_s;
        s2[r] += acc[r] * a_d;
      }
    }
#pragma unroll
    for (int r = 0; r < 4; ++r) {
      float v1 = s1[r], v2 = s2[r];
      v1 += __shfl_xor(v1, 1); v1 += __shfl_xor(v1, 2);
      v1 += __shfl_xor(v1, 4); v1 += __shfl_xor(v1, 8);
      v2 += __shfl_xor(v2, 1); v2 += __shfl_xor(v2, 2);
      v2 += __shfl_xor(v2, 4); v2 += __shfl_xor(v2, 8);
      int node = mt * 16 + quad * 4 + r;
      if (l16 == 0 && node < NN) { asrcL[node] = v1; adstL[node] = v2; }
    }
  }
  __syncthreads();

  for (int layer = 0; layer < 2; ++layer) {
    // ---- masked softmax rows -> alphaB bf16 (cols 102..127 zeroed) ----
    for (int i = wv; i < NN; i += 16) {
      float zi = adstL[i];
      int j1 = 64 + lane;
      bool e0 = (adjPack[i][lane >> 4] >> (lane & 15)) & 1;
      bool e1 = (j1 < NN) && ((adjPack[i][j1 >> 4] >> (j1 & 15)) & 1);
      float p0 = 0.f, p1 = 0.f;
      if (e0) { float z = zi + asrcL[lane]; p0 = __expf(z > 0.f ? z : 0.2f * z); }
      if (e1) { float z = zi + asrcL[j1]; p1 = __expf(z > 0.f ? z : 0.2f * z); }
      float s = p0 + p1;
      s += __shfl_xor(s, 1); s += __shfl_xor(s, 2); s += __shfl_xor(s, 4);
      s += __shfl_xor(s, 8); s += __shfl_xor(s, 16); s += __shfl_xor(s, 32);
      float inv = 1.f / s;
      u.ly.alphaB[i * 136 + lane] = f2bf(p0 * inv);
      u.ly.alphaB[i * 136 + 64 + lane] = f2bf(p1 * inv);
    }
    __syncthreads();
    // ---- aggregate: g = relu(alphaB @ h0tG^T + bias) -> gB ----
    {
      const float* bias = layer ? g1b : g0b;
      for (int tile = wv; tile < 28; tile += 16) {
        int mt = tile >> 2, nt = tile & 3;
        int ar = mt * 16 + l16; if (ar > NN - 1) ar = NN - 1;
        const short* ap = &u.ly.alphaB[ar * 136 + quad * 8];
        const short* bp = hb + (nt * 16 + l16) * 128 + quad * 8;
        f32x4 acc = (f32x4){0.f, 0.f, 0.f, 0.f};
#pragma unroll
        for (int kb = 0; kb < 4; ++kb)
          acc = __builtin_amdgcn_mfma_f32_16x16x32_bf16(*(const bf16x8*)(ap + kb * 32),
                                                        *(const bf16x8*)(bp + kb * 32), acc, 0, 0, 0);
        int f = nt * 16 + l16;
        float bv = bias[f];
#pragma unroll
        for (int r = 0; r < 4; ++r) {
          int i = mt * 16 + quad * 4 + r;
          if (i < NN) u.ly.gB[i * 72 + f] = f2bf(fmaxf(acc[r] + bv, 0.f));
        }
      }
    }
    __syncthreads();
    if (layer == 0) {
      // ---- G1: h1 = gB @ W1 -> h0tG; asrc/adst fused (layer-1 coeffs) ----
      if (wv < 7) {
        int mt = wv;
        int ar = mt * 16 + l16; if (ar > NN - 1) ar = NN - 1;
        const short* ap = &u.ly.gB[ar * 72 + quad * 8];
        float s1[4] = {0.f, 0.f, 0.f, 0.f}, s2[4] = {0.f, 0.f, 0.f, 0.f};
#pragma unroll
        for (int nt = 0; nt < 4; ++nt) {
          const short* bp = w1bT + (nt * 16 + l16) * 64 + quad * 8;
          f32x4 acc = (f32x4){0.f, 0.f, 0.f, 0.f};
#pragma unroll
          for (int kb = 0; kb < 2; ++kb)
            acc = __builtin_amdgcn_mfma_f32_16x16x32_bf16(*(const bf16x8*)(ap + kb * 32),
                                                          *(const bf16x8*)(bp + kb * 32), acc, 0, 0, 0);
          int f = nt * 16 + l16;
          float a_s = g1as[f], a_d = g1ad[f];
#pragma unroll
          for (int r = 0; r < 4; ++r) {
            int node = mt * 16 + quad * 4 + r;
            if (node < NN) hb[f * 128 + node] = f2bf(acc[r]);
            s1[r] += acc[r] * a_s;
            s2[r] += acc[r] * a_d;
          }
        }
#pragma unroll
        for (int r = 0; r < 4; ++r) {
          float v1 = s1[r], v2 = s2[r];
          v1 += __shfl_xor(v1, 1); v1 += __shfl_xor(v1, 2);
          v1 += __shfl_xor(v1, 4); v1 += __shfl_xor(v1, 8);
          v2 += __shfl_xor(v2, 1); v2 += __shfl_xor(v2, 2);
          v2 += __shfl_xor(v2, 4); v2 += __shfl_xor(v2, 8);
          int node = mt * 16 + quad * 4 + r;
          if (l16 == 0 && node < NN) { asrcL[node] = v1; adstL[node] = v2; }
        }
      }
      __syncthreads();
    }
  }

  // ---- gate: gwN = sigmoid(gB @ wg2a^T + b) (alphaB region reused for wgL/gwN) ----
  float* wgL = (float*)&u.ly.alphaB[0];
  float* gwN = wgL + 512;
  if (t < 512) wgL[t] = wg2a[t];
  __syncthreads();
  if (t < NN * NH) {
    int n = t >> 3, h = t & 7;
    float z = bg2a[h];
#pragma unroll
    for (int c = 0; c < GD; ++c) z += bf2f(u.ly.gB[n * 72 + c]) * wgL[h * 64 + c];
    gwN[n * 8 + h] = 1.f / (1.f + __expf(-z));
  }
  __syncthreads();

  // ---- tail: position-space gwp + 1024-bit posadj rows ----
  {
    int p = t;
    int n = nodeofL[p];
#pragma unroll
    for (int h = 0; h < 8; ++h)
      gwp[(size_t)(b * 8 + h) * 1024 + p] = (n >= 0) ? gwN[n * 8 + h] : 0.f;
    unsigned long long m[16];
#pragma unroll
    for (int w = 0; w < 16; ++w) m[w] = 0;
    if (n >= 0) {
      for (int w = 0; w < 7; ++w) {
        unsigned bits = adjPack[n][w];
        while (bits) {
          int j = __ffs(bits) - 1;
          int pj = topiL[w * 16 + j];
          m[pj >> 6] |= 1ull << (pj & 63);
          bits &= bits - 1;
        }
      }
    }
#pragma unroll
    for (int w = 0; w < 16; ++w)
      posadj[((size_t)b * 16 + w) * 1024 + p] = m[w];
  }
}

// ---------------- QKV split-bf16 MFMA GEMM (32-col tiles, LDS-staged coalesced stores) ----------------
// grid(128, 24): x = M-block of 64 rows; y: qi = y/8 (0=Q,1=K,2=V), n0 = (y%8)*32.
// V^T is stored with per-64-chunk key permutation sigma(j) = (j&15)*4 + (j>>4) to match attn's P layout.
__global__ __launch_bounds__(256, 4) void qkv_k(const short* __restrict__ xth,
                                                const short* __restrict__ xtl,
                                                const short* __restrict__ wqh,
                                                const short* __restrict__ wql,
                                                short* __restrict__ qhp, short* __restrict__ qlp,
                                                short* __restrict__ khp, short* __restrict__ klp,
                                                short* __restrict__ vtp) {
  __shared__ short st_s[4][16 * 40 * 2];   // per-wave Q/K hi|lo staging; V aliases block-wide
  int t = threadIdx.x, wid = t >> 6, lane = t & 63, quad = lane >> 4, l16 = lane & 15;
  int m0 = blockIdx.x * 64, y = blockIdx.y;
  int b = m0 >> 10;
  int row = m0 + wid * 16 + l16;
  int p_base = (m0 & 1023) + wid * 16;
  int qi = y >> 3, n0 = (y & 7) * 32;
  const short* wh = wqh + ((size_t)qi * 256 + n0) * 256;
  const short* wl = wql + ((size_t)qi * 256 + n0) * 256;
  const short* arh = xth + (size_t)row * 256 + quad * 8;
  const short* arl = xtl + (size_t)row * 256 + quad * 8;
  f32x4 acc[2];
  acc[0] = (f32x4){0.f, 0.f, 0.f, 0.f};
  acc[1] = (f32x4){0.f, 0.f, 0.f, 0.f};
#pragma unroll
  for (int kb = 0; kb < 8; ++kb) {
    bf16x8 ah = *(const bf16x8*)(arh + kb * 32);
    bf16x8 al = *(const bf16x8*)(arl + kb * 32);
#pragma unroll
    for (int nt = 0; nt < 2; ++nt) {
      size_t wo = (size_t)(nt * 16 + l16) * 256 + kb * 32 + quad * 8;
      bf16x8 bh_ = *(const bf16x8*)(wh + wo);
      bf16x8 bl_ = *(const bf16x8*)(wl + wo);
      acc[nt] = __builtin_amdgcn_mfma_f32_16x16x32_bf16(ah, bh_, acc[nt], 0, 0, 0);
      acc[nt] = __builtin_amdgcn_mfma_f32_16x16x32_bf16(ah, bl_, acc[nt], 0, 0, 0);
      acc[nt] = __builtin_amdgcn_mfma_f32_16x16x32_bf16(al, bh_, acc[nt], 0, 0, 0);
    }
  }
  int h = n0 >> 5;
  if (qi < 2) {
    const float scale = (qi == 0) ? 0.17677669529663687f : 1.f;
    short* hp = (qi == 0) ? qhp : khp;
    short* lp = (qi == 0) ? qlp : klp;
    short* vsh = &st_s[wid][0];
    short* vsl = &st_s[wid][640];
#pragma unroll
    for (int nt = 0; nt < 2; ++nt) {
      int d = nt * 16 + l16;
#pragma unroll
      for (int r = 0; r < 4; ++r) {
        float v = acc[nt][r] * scale;
        short hi = f2bf(v);
        vsh[(quad * 4 + r) * 40 + d] = hi;
        vsl[(quad * 4 + r) * 40 + d] = f2bf(v - bf2f(hi));
      }
    }
    int orow = lane >> 2, seg = lane & 3;
    size_t e = ((size_t)(b * 8 + h) * 1024 + p_base + orow) * 32 + seg * 8;
    *(bf16x8*)(hp + e) = *(const bf16x8*)(vsh + orow * 40 + seg * 8);
    *(bf16x8*)(lp + e) = *(const bf16x8*)(vsl + orow * 40 + seg * 8);
  } else {
    // V: block-level sigma-permuted transpose -> vt[bh][d][chunk + sigma]
    short* vsv = &st_s[0][0];   // 32 x 72
#pragma unroll
    for (int nt = 0; nt < 2; ++nt) {
      int d = nt * 16 + l16;
#pragma unroll
      for (int r = 0; r < 4; ++r)
        vsv[d * 72 + (quad * 4 + r) * 4 + wid] = f2bf(acc[nt][r]);
    }
    __syncthreads();
    int d = t >> 3, g = t & 7;
    size_t rb = ((size_t)(b * 8 + h) * 32 + d) * 1024 + (m0 & 1023) + g * 8;
    *(bf16x8*)(vtp + rb) = *(const bf16x8*)(vsv + d * 72 + g * 8);
  }
}

// ---------------- flash attention: bitmask graph-mod, sigma-P layout, deferred-sum softmax ----------------
__global__ __launch_bounds__(256, 4) void attn_k(const short* __restrict__ qh,
                                                 const short* __restrict__ ql,
                                                 const short* __restrict__ kh,
                                                 const short* __restrict__ kl,
                                                 const short* __restrict__ vt,
                                                 const float* __restrict__ gwp,
                                                 const unsigned long long* __restrict__ posadj,
                                                 short* __restrict__ aoh,
                                                 short* __restrict__ aol) {
  __shared__ __align__(16) short p_s[4][16 * 72];  // per-wave P (sigma layout) / overlay O f32 16x36
  __shared__ float aw_s[4][16];
  int t = threadIdx.x;
  int wid = t >> 6, lane = t & 63, quad = lane >> 4, l16 = lane & 15;
  int bh = blockIdx.x, b = bh >> 3, h = bh & 7;   // bh fastest -> co-XCD q-tiles
  int q0 = blockIdx.y * 64 + wid * 16;
  size_t base = (size_t)bh * 32768;
  short* pw = &p_s[wid][0];
  float* aw = &aw_s[wid][0];

  size_t qoff = base + (size_t)(q0 + l16) * 32 + quad * 8;
  bf16x8 qhf = *(const bf16x8*)(qh + qoff);
  bf16x8 qlf = *(const bf16x8*)(ql + qoff);

  const float* gwpBH = gwp + (size_t)bh * 1024;
  const unsigned long long* paB = posadj + (size_t)b * 16 * 1024;
  float grq[4];
#pragma unroll
  for (int r = 0; r < 4; ++r) grq[r] = gwpBH[q0 + quad * 4 + r];

  f32x4 ot[2];
  ot[0] = (f32x4){0.f, 0.f, 0.f, 0.f};
  ot[1] = (f32x4){0.f, 0.f, 0.f, 0.f};
  float l_r[4] = {0.f, 0.f, 0.f, 0.f};

  for (int ch = 0; ch < 16; ++ch) {
    int c0 = ch * 64;
    bf16x8 khf[4], klf[4];
#pragma unroll
    for (int ni = 0; ni < 4; ++ni) {
      size_t off = base + (size_t)(c0 + ni * 16 + l16) * 32 + quad * 8;
      khf[ni] = *(const bf16x8*)(kh + off);
      klf[ni] = *(const bf16x8*)(kl + off);
    }
    bf16x8 vaf[2][2];
#pragma unroll
    for (int mi = 0; mi < 2; ++mi)
#pragma unroll
      for (int ks = 0; ks < 2; ++ks)
        vaf[mi][ks] = *(const bf16x8*)(vt + base + (size_t)(mi * 16 + l16) * 1024 +
                                       c0 + ks * 32 + quad * 8);
    float gc[4];
#pragma unroll
    for (int ni = 0; ni < 4; ++ni) gc[ni] = gwpBH[c0 + ni * 16 + l16];
    unsigned long long mr[4];
#pragma unroll
    for (int r = 0; r < 4; ++r)
      mr[r] = paB[(size_t)ch * 1024 + q0 + quad * 4 + r];
    f32x4 s[4];
#pragma unroll
    for (int ni = 0; ni < 4; ++ni) {
      f32x4 a = (f32x4){0.f, 0.f, 0.f, 0.f};
      a = __builtin_amdgcn_mfma_f32_16x16x32_bf16(qhf, khf[ni], a, 0, 0, 0);
      a = __builtin_amdgcn_mfma_f32_16x16x32_bf16(qhf, klf[ni], a, 0, 0, 0);
      a = __builtin_amdgcn_mfma_f32_16x16x32_bf16(qlf, khf[ni], a, 0, 0, 0);
      s[ni] = a;
    }
#pragma unroll
    for (int r = 0; r < 4; ++r) {
#pragma unroll
      for (int ni = 0; ni < 4; ++ni) {
        bool bit = (mr[r] >> (ni * 16 + l16)) & 1ull;
        s[ni][r] += bit ? grq[r] * gc[ni] : 0.f;
      }
    }
    // p = exp(s) (bounded scores); store in sigma layout: key ni*16+l16 -> col l16*4+ni
#pragma unroll
    for (int r = 0; r < 4; ++r) {
      float e0 = __expf(s[0][r]);
      float e1 = __expf(s[1][r]);
      float e2 = __expf(s[2][r]);
      float e3 = __expf(s[3][r]);
      l_r[r] += (e0 + e1) + (e2 + e3);
      short4 pq = {f2bf(e0), f2bf(e1), f2bf(e2), f2bf(e3)};
      *(short4*)(pw + (quad * 4 + r) * 72 + l16 * 4) = pq;
    }
#pragma unroll
    for (int ks = 0; ks < 2; ++ks) {
      bf16x8 pb = *(const bf16x8*)(pw + l16 * 72 + ks * 32 + quad * 8);
      ot[0] = __builtin_amdgcn_mfma_f32_16x16x32_bf16(vaf[0][ks], pb, ot[0], 0, 0, 0);
      ot[1] = __builtin_amdgcn_mfma_f32_16x16x32_bf16(vaf[1][ks], pb, ot[1], 0, 0, 0);
    }
  }
  // final row-sum reduce, invert, transpose via per-wave LDS, hi/lo bf16 store
#pragma unroll
  for (int r = 0; r < 4; ++r) {
    float ls = l_r[r];
    ls += __shfl_xor(ls, 1);
    ls += __shfl_xor(ls, 2);
    ls += __shfl_xor(ls, 4);
    ls += __shfl_xor(ls, 8);
    if (l16 == 0) aw[quad * 4 + r] = 1.f / ls;
  }
  float li = aw[l16];
  ot[0] *= li;
  ot[1] *= li;
  float* os = (float*)pw;
#pragma unroll
  for (int mi = 0; mi < 2; ++mi)
#pragma unroll
    for (int r = 0; r < 4; ++r)
      os[l16 * 36 + mi * 16 + quad * 4 + r] = ot[mi][r];
  int qr2 = lane >> 2, dg = (lane & 3) * 8;
  float f[8];
  *(float4*)&f[0] = *(float4*)&os[qr2 * 36 + dg];
  *(float4*)&f[4] = *(float4*)&os[qr2 * 36 + dg + 4];
  bf16x8 hv, lv;
#pragma unroll
  for (int j = 0; j < 8; ++j) {
    hv[j] = f2bf(f[j]);
    lv[j] = f2bf(f[j] - bf2f(hv[j]));
  }
  size_t ob = (size_t)(b * 1024 + q0 + qr2) * 256 + h * 32 + dg;
  *(bf16x8*)(aoh + ob) = hv;
  *(bf16x8*)(aol + ob) = lv;
}

// ---------------- proj split-bf16 MFMA GEMM (32-col tiles) + bias + transposed store ----------------
__global__ __launch_bounds__(256, 4) void proj_k(const short* __restrict__ aoh,
                                                 const short* __restrict__ aol,
                                                 const short* __restrict__ wph,
                                                 const short* __restrict__ wpl,
                                                 const float* __restrict__ bias,
                                                 float* __restrict__ out) {
  __shared__ float os_s[4][32 * 20];
  int t = threadIdx.x, wid = t >> 6, lane = t & 63, quad = lane >> 4, l16 = lane & 15;
  int m0 = blockIdx.x * 64, n0 = blockIdx.y * 32;
  int b = m0 >> 10;
  int row = m0 + wid * 16 + l16;
  int p_base = (m0 & 1023) + wid * 16;
  const short* arh = aoh + (size_t)row * 256 + quad * 8;
  const short* arl = aol + (size_t)row * 256 + quad * 8;
  f32x4 acc[2];
  acc[0] = (f32x4){0.f, 0.f, 0.f, 0.f};
  acc[1] = (f32x4){0.f, 0.f, 0.f, 0.f};
#pragma unroll
  for (int kb = 0; kb < 8; ++kb) {
    bf16x8 ah = *(const bf16x8*)(arh + kb * 32);
    bf16x8 al = *(const bf16x8*)(arl + kb * 32);
#pragma unroll
    for (int nt = 0; nt < 2; ++nt) {
      size_t wo = (size_t)(n0 + nt * 16 + l16) * 256 + kb * 32 + quad * 8;
      bf16x8 bh_ = *(const bf16x8*)(wph + wo);
      bf16x8 bl_ = *(const bf16x8*)(wpl + wo);
      acc[nt] = __builtin_amdgcn_mfma_f32_16x16x32_bf16(ah, bh_, acc[nt], 0, 0, 0);
      acc[nt] = __builtin_amdgcn_mfma_f32_16x16x32_bf16(ah, bl_, acc[nt], 0, 0, 0);
      acc[nt] = __builtin_amdgcn_mfma_f32_16x16x32_bf16(al, bh_, acc[nt], 0, 0, 0);
    }
  }
  float* os = &os_s[wid][0];
#pragma unroll
  for (int nt = 0; nt < 2; ++nt) {
    float bv = bias[n0 + nt * 16 + l16];
#pragma unroll
    for (int r = 0; r < 4; ++r)
      os[(nt * 16 + l16) * 20 + quad * 4 + r] = acc[nt][r] + bv;
  }
  int cl = lane >> 1, hf = lane & 1;
  int c = n0 + cl;
  float* orow = out + ((size_t)(b * 256 + c)) * 1024 + p_base;
  *(float4*)(orow + hf * 8) = *(float4*)&os[cl * 20 + hf * 8];
  *(float4*)(orow + hf * 8 + 4) = *(float4*)&os[cl * 20 + hf * 8 + 4];
}

extern "C" void kernel_launch(void* const* d_in, const int* in_sizes, int n_in,
                              void* d_out, int out_size, void* d_ws, size_t ws_size,
                              hipStream_t stream) {
  const float* x      = (const float*)d_in[0];
  const float* w_qkv  = (const float*)d_in[1];
  const float* w_proj = (const float*)d_in[2];
  const float* b_proj = (const float*)d_in[3];
  const float* g0W    = (const float*)d_in[4];
  const float* g0as   = (const float*)d_in[5];
  const float* g0ad   = (const float*)d_in[6];
  const float* g0b    = (const float*)d_in[7];
  const float* g1W    = (const float*)d_in[8];
  const float* g1as   = (const float*)d_in[9];
  const float* g1ad   = (const float*)d_in[10];
  const float* g1b    = (const float*)d_in[11];
  const float* wg2a   = (const float*)d_in[12];
  const float* bg2a   = (const float*)d_in[13];
  float* out = (float*)d_out;
  float* ws = (float*)d_ws;

  size_t o = 0;
  auto alloc = [&](size_t nf) { float* p = ws + o; o += (nf + 15) & ~(size_t)15; return p; };
  float* imp    = alloc(8 * 1024);
  short* w0bT   = (short*)alloc(256 * 64 / 2);
  short* w1bT   = (short*)alloc(64 * 64 / 2);
  short* h0tG   = (short*)alloc(8 * 64 * 128 / 2);
  float* gwp    = alloc(64 * 1024);
  unsigned long long* posadj = (unsigned long long*)alloc(8 * 16 * 1024 * 2);
  short* xth    = (short*)alloc(1048576);
  short* xtl    = (short*)alloc(1048576);
  short* wqh    = (short*)alloc(98304);
  short* wql    = (short*)alloc(98304);
  short* wph    = (short*)alloc(32768);
  short* wpl    = (short*)alloc(32768);
  short* qh     = (short*)alloc(1048576);
  short* ql     = (short*)alloc(1048576);
  short* kh     = (short*)alloc(1048576);
  short* kl     = (short*)alloc(1048576);
  short* vt     = (short*)alloc(1048576);
  short* aoh    = (short*)alloc(1048576);
  short* aol    = (short*)alloc(1048576);
  if (ws_size < o * sizeof(float)) return;

  importance_k<<<256, 256, 0, stream>>>(x, imp);
  wsplitprep_k<<<1104, 256, 0, stream>>>(w_qkv, w_proj, g0W, g1W,
                                         wqh, wql, wph, wpl, w0bT, w1bT);
  xsplit_k<<<dim3(16, 4, 8), 256, 0, stream>>>(x, xth, xtl);
  graph_k<<<8, 1024, 0, stream>>>(imp, xth, xtl, w0bT, w1bT,
                                  g0as, g0ad, g0b, g1as, g1ad, g1b,
                                  wg2a, bg2a, h0tG, gwp, posadj);
  qkv_k<<<dim3(128, 24), 256, 0, stream>>>(xth, xtl, wqh, wql, qh, ql, kh, kl, vt);
  attn_k<<<dim3(64, 16), 256, 0, stream>>>(qh, ql, kh, kl, vt, gwp, posadj, aoh, aol);
  proj_k<<<dim3(128, 8), 256, 0, stream>>>(aoh, aol, wph, wpl, b_proj, out);
}